// Round 8
// baseline (1855.955 us; speedup 1.0000x reference)
//
#include <hip/hip_runtime.h>

// MatchLSTM forward (Round 23): G3 L2 set-conflict fix.
//   R22 post-mortem: FETCH stayed 330MB -> G3 self-thrash found by address
//   arithmetic: old layout [(tp*128+b)*1536] puts a block's 32 tp-chunks at
//   stride 768KB = 3 x 256KB (L2 set period) -> all 32 chunks in ONE set
//   window, 32 ways needed vs 16 -> ~50% miss on the 1.6GB re-read ->
//   latency-bound. R23: G3 repacked BLOCK-CONTIGUOUS [b][tp][gate][j][par]
//   (196KB contiguous per block). Per-XCD set: 16x196KB + Wm 0.5MB = 3.6MB
//   fits 16-way 4MB L2 with no self-conflict. Only g3pack epilogue index +
//   phaseB t-sum pointer change; numerics identical.
// Everything else: R22 verbatim (validated; absmax 9.77e-4).

#define DEV static __device__ __forceinline__

DEV float fast_sigmoid(float x) { return 1.0f / (1.0f + __expf(-x)); }
DEV float fast_tanh(float x)    { return 1.0f - 2.0f / (__expf(2.0f * x) + 1.0f); }

DEV unsigned f2bf(float x) {
    unsigned v = __float_as_uint(x);
    return (v + 0x7FFFu + ((v >> 16) & 1u)) >> 16;
}
DEV float blo(unsigned u) { return __uint_as_float(u << 16); }
DEV float bhi(unsigned u) { return __uint_as_float(u & 0xFFFF0000u); }

DEV float ntload(const float* p) { return __builtin_nontemporal_load(p); }

typedef __attribute__((ext_vector_type(8))) short bfrag;   // 8 bf16
typedef __attribute__((ext_vector_type(4))) float ffrag;   // 4 fp32 acc

DEV void cvt_hilo(const float* v, bfrag& hi, bfrag& lo)
{
#pragma unroll
    for (int z = 0; z < 8; ++z) {
        unsigned h = f2bf(v[z]);
        hi[z] = (short)h;
        lo[z] = (short)f2bf(v[z] - __uint_as_float(h << 16));
    }
}

// ---------------------------------------------------------------------------
// MFMA GEMM (validated R14): C[M][512] = A[M][512] . W[512][512]^T, bf16x3.
// ---------------------------------------------------------------------------
__global__ __launch_bounds__(256) void mfma_nt_kernel(
    const float* __restrict__ A, const float* __restrict__ W,
    float* __restrict__ C)
{
    const int wv   = threadIdx.x >> 6;
    const int lane = threadIdx.x & 63;
    const int row  = lane & 15;
    const int quad = lane >> 4;
    const int m0 = blockIdx.x * 64 + wv * 16;
    const int n0 = blockIdx.y * 64;

    ffrag acc[4];
#pragma unroll
    for (int n = 0; n < 4; ++n)
#pragma unroll
        for (int r = 0; r < 4; ++r) acc[n][r] = 0.0f;

    for (int k0 = 0; k0 < 512; k0 += 32) {
        const float* ap = A + (size_t)(m0 + row) * 512 + k0 + quad * 8;
        float4 aA = *(const float4*)ap;
        float4 aB = *(const float4*)(ap + 4);
        float av[8] = {aA.x, aA.y, aA.z, aA.w, aB.x, aB.y, aB.z, aB.w};
        bfrag ahi, alo;
        cvt_hilo(av, ahi, alo);
#pragma unroll
        for (int n = 0; n < 4; ++n) {
            const float* wp = W + (size_t)(n0 + n * 16 + row) * 512 + k0 + quad * 8;
            float4 wA = *(const float4*)wp;
            float4 wB = *(const float4*)(wp + 4);
            float wvv[8] = {wA.x, wA.y, wA.z, wA.w, wB.x, wB.y, wB.z, wB.w};
            bfrag whi, wlo;
            cvt_hilo(wvv, whi, wlo);
            acc[n] = __builtin_amdgcn_mfma_f32_16x16x32_bf16(ahi, whi, acc[n], 0, 0, 0);
            acc[n] = __builtin_amdgcn_mfma_f32_16x16x32_bf16(alo, whi, acc[n], 0, 0, 0);
            acc[n] = __builtin_amdgcn_mfma_f32_16x16x32_bf16(ahi, wlo, acc[n], 0, 0, 0);
        }
    }
#pragma unroll
    for (int n = 0; n < 4; ++n)
#pragma unroll
        for (int r = 0; r < 4; ++r)
            C[(size_t)(m0 + quad * 4 + r) * 512 + n0 + n * 16 + row] = acc[n][r];
}

// ---------------------------------------------------------------------------
// 3-gate MFMA GEMM (validated R15): fp32 out + biases.
// ---------------------------------------------------------------------------
template<int GATHER>
__global__ __launch_bounds__(256) void mfma_g3_kernel(
    const float* __restrict__ A, const int* __restrict__ gidx,
    int lda, int K,
    const float* __restrict__ W, int ldw,
    const float* __restrict__ bias1, const float* __restrict__ bias2,
    float* __restrict__ out)
{
    const int wv   = threadIdx.x >> 6;
    const int lane = threadIdx.x & 63;
    const int row  = lane & 15;
    const int quad = lane >> 4;
    const int m0   = blockIdx.x * 64 + wv * 16;
    const int gate = blockIdx.y >> 3;
    const int gbase = (gate == 0) ? 0 : (gate == 1 ? 1024 : 1536);
    const int j0   = (blockIdx.y & 7) * 64;

    const int arow = GATHER ? gidx[m0 + row] : (m0 + row);

    ffrag acc[4];
#pragma unroll
    for (int n = 0; n < 4; ++n)
#pragma unroll
        for (int r = 0; r < 4; ++r) acc[n][r] = 0.0f;

    for (int k0 = 0; k0 < K; k0 += 32) {
        const bool tail = (k0 + 32 > K);
        float av[8];
        if (!tail) {
            const float* ap = A + (size_t)arow * lda + k0 + quad * 8;
            float4 aA = *(const float4*)ap;
            float4 aB = *(const float4*)(ap + 4);
            av[0]=aA.x; av[1]=aA.y; av[2]=aA.z; av[3]=aA.w;
            av[4]=aB.x; av[5]=aB.y; av[6]=aB.z; av[7]=aB.w;
        } else {
#pragma unroll
            for (int z = 0; z < 8; ++z) {
                int kk = k0 + quad * 8 + z;
                av[z] = (kk < K) ? A[(size_t)arow * lda + kk] : 0.0f;
            }
        }
        bfrag ahi, alo;
        cvt_hilo(av, ahi, alo);
#pragma unroll
        for (int n = 0; n < 4; ++n) {
            const int wrow = gbase + j0 + n * 16 + row;
            float wvv[8];
            if (!tail) {
                const float* wp = W + (size_t)wrow * ldw + k0 + quad * 8;
                float4 wA = *(const float4*)wp;
                float4 wB = *(const float4*)(wp + 4);
                wvv[0]=wA.x; wvv[1]=wA.y; wvv[2]=wA.z; wvv[3]=wA.w;
                wvv[4]=wB.x; wvv[5]=wB.y; wvv[6]=wB.z; wvv[7]=wB.w;
            } else {
#pragma unroll
                for (int z = 0; z < 8; ++z) {
                    int kk = k0 + quad * 8 + z;
                    wvv[z] = (kk < K) ? W[(size_t)wrow * ldw + kk] : 0.0f;
                }
            }
            bfrag whi, wlo;
            cvt_hilo(wvv, whi, wlo);
            acc[n] = __builtin_amdgcn_mfma_f32_16x16x32_bf16(ahi, whi, acc[n], 0, 0, 0);
            acc[n] = __builtin_amdgcn_mfma_f32_16x16x32_bf16(alo, whi, acc[n], 0, 0, 0);
            acc[n] = __builtin_amdgcn_mfma_f32_16x16x32_bf16(ahi, wlo, acc[n], 0, 0, 0);
        }
    }
#pragma unroll
    for (int n = 0; n < 4; ++n) {
        const int j = j0 + n * 16 + row;
        const float bb = bias1[gbase + j] + bias2[gbase + j];
#pragma unroll
        for (int r = 0; r < 4; ++r) {
            const int m = m0 + quad * 4 + r;
            out[((size_t)m * 3 + gate) * 512 + j] = acc[n][r] + bb;
        }
    }
}

// ---------------------------------------------------------------------------
// G3 GEMM (R23): G3[t,b,:] = W3 . h_s[t,b,:], bf16 pair-packed,
// BLOCK-CONTIGUOUS layout: ushort idx =
//   (((b*32 + (t>>1)) * 1536) + gate*512 + j)*2 + (t&1)
// -> each phase-B block's 196KB footprint is one contiguous window
//    (kills the 768KB-stride L2 set self-conflict of the R21/R22 layout).
// ---------------------------------------------------------------------------
__global__ __launch_bounds__(256) void g3pack_kernel(
    const float* __restrict__ A,            // Rh: 4096 x 512
    const float* __restrict__ W,            // Wih_m, ldw 1024
    unsigned short* __restrict__ G3s,
    int mbase)                              // 0 or 4096
{
    const int wv   = threadIdx.x >> 6;
    const int lane = threadIdx.x & 63;
    const int row  = lane & 15;
    const int quad = lane >> 4;
    const int m0   = blockIdx.x * 64 + wv * 16;
    const int gate = blockIdx.y >> 3;
    const int gbase = (gate == 0) ? 0 : (gate == 1 ? 1024 : 1536);
    const int j0   = (blockIdx.y & 7) * 64;

    ffrag acc[4];
#pragma unroll
    for (int n = 0; n < 4; ++n)
#pragma unroll
        for (int r = 0; r < 4; ++r) acc[n][r] = 0.0f;

    for (int k0 = 0; k0 < 512; k0 += 32) {
        const float* ap = A + (size_t)(m0 + row) * 512 + k0 + quad * 8;
        float4 aA = *(const float4*)ap;
        float4 aB = *(const float4*)(ap + 4);
        float av[8] = {aA.x, aA.y, aA.z, aA.w, aB.x, aB.y, aB.z, aB.w};
        bfrag ahi, alo;
        cvt_hilo(av, ahi, alo);
#pragma unroll
        for (int n = 0; n < 4; ++n) {
            const int wrow = gbase + j0 + n * 16 + row;
            const float* wp = W + (size_t)wrow * 1024 + k0 + quad * 8;
            float4 wA = *(const float4*)wp;
            float4 wB = *(const float4*)(wp + 4);
            float wvv[8] = {wA.x, wA.y, wA.z, wA.w, wB.x, wB.y, wB.z, wB.w};
            bfrag whi, wlo;
            cvt_hilo(wvv, whi, wlo);
            acc[n] = __builtin_amdgcn_mfma_f32_16x16x32_bf16(ahi, whi, acc[n], 0, 0, 0);
            acc[n] = __builtin_amdgcn_mfma_f32_16x16x32_bf16(alo, whi, acc[n], 0, 0, 0);
            acc[n] = __builtin_amdgcn_mfma_f32_16x16x32_bf16(ahi, wlo, acc[n], 0, 0, 0);
        }
    }
#pragma unroll
    for (int n = 0; n < 4; ++n) {
        const int j = j0 + n * 16 + row;
#pragma unroll
        for (int r = 0; r < 4; ++r) {
            const int mg = mbase + m0 + quad * 4 + r;
            const int t = mg >> 7, b = mg & 127;
            size_t idx = (((size_t)b * 32 + (t >> 1)) * 1536
                          + gate * 512 + j) * 2 + (t & 1);
            G3s[idx] = (unsigned short)f2bf(acc[n][r]);
        }
    }
}

// ---------------------------------------------------------------------------
// Encoder gate math (validated R15).
// ---------------------------------------------------------------------------
__global__ __launch_bounds__(256) void enc_gates_kernel(
    const float* __restrict__ P, float* __restrict__ h)
{
    const int i = blockIdx.x * 256 + threadIdx.x;
    const int m = i >> 7;
    const int j4 = (i & 127) * 4;
    const float* p = P + (size_t)m * 1536 + j4;
    float4 gi = *(const float4*)p;
    float4 gg = *(const float4*)(p + 512);
    float4 go = *(const float4*)(p + 1024);
    float4 r;
    r.x = fast_sigmoid(go.x) * fast_tanh(fast_sigmoid(gi.x) * fast_tanh(gg.x));
    r.y = fast_sigmoid(go.y) * fast_tanh(fast_sigmoid(gi.y) * fast_tanh(gg.y));
    r.z = fast_sigmoid(go.z) * fast_tanh(fast_sigmoid(gi.z) * fast_tanh(gg.z));
    r.w = fast_sigmoid(go.w) * fast_tanh(fast_sigmoid(gi.w) * fast_tanh(gg.w));
    *(float4*)&h[(size_t)m * 512 + j4] = r;
}

// ---------------------------------------------------------------------------
// Wm pack (validated R19): [kc][nt][lane] tile-interleaved.
// ---------------------------------------------------------------------------
__global__ __launch_bounds__(256) void pack_wm_kernel(
    const float* __restrict__ Wm, unsigned* __restrict__ WmB)
{
    int i = blockIdx.x * 256 + threadIdx.x;           // 0 .. 131071
    int u = i & 3, lane = (i >> 2) & 63;
    int nt = (i >> 8) & 31, kc = i >> 13;
    int row = nt * 16 + (lane & 15);
    int k = kc * 32 + ((lane >> 4) << 3) + u * 2;
    unsigned lo = f2bf(Wm[(size_t)row * 512 + k]);
    unsigned hi = f2bf(Wm[(size_t)row * 512 + k + 1]);
    WmB[i] = lo | (hi << 16);
}

// ---------------------------------------------------------------------------
// Phase B (Round 23): R22 + block-contiguous G3 addressing.
// ---------------------------------------------------------------------------
__global__ __launch_bounds__(1024) void phaseB_kernel(
    const float* __restrict__ pre_s, const float* __restrict__ pre_t,
    const float* __restrict__ pre_m_h,
    const unsigned* __restrict__ WmB, const unsigned* __restrict__ G3u,
    const float* __restrict__ w_e,
    const float* __restrict__ fc_w,  const float* __restrict__ fc_b,
    float* __restrict__ out)
{
    extern __shared__ __align__(16) float psL[];      // 64*512 fp32 = 128KB
    __shared__ __align__(16) float hm[512];
    __shared__ __align__(16) float base[512];
    __shared__ __align__(16) float wesh[512];
    __shared__ __align__(16) float sc[64];
    __shared__ __align__(16) float red3[3 * 2 * 512];
    __shared__ __align__(16) unsigned short hmh[512];
    __shared__ __align__(16) unsigned short hml[512];

    const int b    = blockIdx.x;
    const int tid  = threadIdx.x;
    const int wv   = tid >> 6;
    const int lane = tid & 63;
    const int j    = tid & 511;
    const int kh   = tid >> 9;
    const int quad = lane >> 4;

    if (tid < 512) {
        wesh[tid] = w_e[tid];
        hm[tid] = 0.0f; hmh[tid] = 0; hml[tid] = 0;
    }
    // pre_s[t,b,:] -> LDS once (exact fp32), reused all 64 steps
    for (int i = tid; i < 32768; i += 1024) {
        int t = i >> 9, h = i & 511;
        psL[i] = ntload(&pre_s[((size_t)t * 128 + b) * 512 + h]);
    }
    __syncthreads();

    for (int k = 0; k < 64; ++k) {
        // ---- GEMV1 (K-split): partials for base = Wm . hm
        {
            const int kh2 = wv >> 3;               // K-half 0/1
            const int tp  = (wv & 7) * 4;          // 4 tiles per wave
            ffrag a0 = {0.0f,0.0f,0.0f,0.0f}, a1 = {0.0f,0.0f,0.0f,0.0f};
            ffrag a2 = {0.0f,0.0f,0.0f,0.0f}, a3 = {0.0f,0.0f,0.0f,0.0f};
            const uint4* wp = (const uint4*)WmB
                            + ((size_t)(kh2 * 8) * 32 + tp) * 64 + lane;
            const unsigned short* ab = ((lane & 8) == 0) ? hmh : hml;
#pragma unroll 1
            for (int kc = 0; kc < 8; ++kc) {
                bfrag a  = *(const bfrag*)&ab[(kh2 * 8 + kc) * 32 + quad * 8];
                bfrag w0 = *(const bfrag*)(wp);
                bfrag w1 = *(const bfrag*)(wp + 64);
                bfrag w2 = *(const bfrag*)(wp + 128);
                bfrag w3 = *(const bfrag*)(wp + 192);
                a0 = __builtin_amdgcn_mfma_f32_16x16x32_bf16(a, w0, a0, 0, 0, 0);
                a1 = __builtin_amdgcn_mfma_f32_16x16x32_bf16(a, w1, a1, 0, 0, 0);
                a2 = __builtin_amdgcn_mfma_f32_16x16x32_bf16(a, w2, a2, 0, 0, 0);
                a3 = __builtin_amdgcn_mfma_f32_16x16x32_bf16(a, w3, a3, 0, 0, 0);
                wp += 2048;                        // next kc (32 tiles * 64)
            }
            float s0 = a0[0] + __shfl_xor(a0[0], 32);
            float s1 = a1[0] + __shfl_xor(a1[0], 32);
            float s2 = a2[0] + __shfl_xor(a2[0], 32);
            float s3 = a3[0] + __shfl_xor(a3[0], 32);
            if (lane < 16) {
                float* rr = &red3[kh2 * 512];
                rr[(tp + 0) * 16 + lane] = s0;
                rr[(tp + 1) * 16 + lane] = s1;
                rr[(tp + 2) * 16 + lane] = s2;
                rr[(tp + 3) * 16 + lane] = s3;
            }
        }
        __syncthreads();
        if (tid < 512)
            base[tid] = red3[tid] + red3[512 + tid]
                      + ntload(&pre_t[((size_t)k * 128 + b) * 512 + tid]);
        __syncthreads();

        // ---- attention scores: e[t] = w_e . tanh(psL[t] + base)  (all LDS)
#pragma unroll
        for (int tt = 0; tt < 4; ++tt) {
            int t = wv * 4 + tt;
            const float* ps = &psL[t * 512];
            float p = 0.0f;
#pragma unroll
            for (int u = 0; u < 8; ++u) {
                int h = lane + 64 * u;
                p += wesh[h] * fast_tanh(ps[h] + base[h]);
            }
#pragma unroll
            for (int off = 32; off; off >>= 1) p += __shfl_xor(p, off);
            if (lane == 0) sc[t] = p;
        }
        __syncthreads();

        // ---- softmax over 64 premise positions
        if (wv == 0) {
            float s = sc[lane], mx = s;
#pragma unroll
            for (int off = 32; off; off >>= 1) mx = fmaxf(mx, __shfl_xor(mx, off));
            float e = __expf(s - mx), sum = e;
#pragma unroll
            for (int off = 32; off; off >>= 1) sum += __shfl_xor(sum, off);
            sc[lane] = e / sum;
        }
        __syncthreads();

        // ---- gates partials = sum_t alpha_t * G3[t,b,:]  (block-contiguous)
        {
            const unsigned* gb = G3u + ((size_t)b * 32 + kh * 16) * 1536 + j;
            float p0 = 0.0f, p1 = 0.0f, p2 = 0.0f;
#pragma unroll 4
            for (int tpi = 0; tpi < 16; ++tpi) {
                const unsigned* gt = gb + (size_t)tpi * 1536;
                unsigned u0 = gt[0];
                unsigned u1 = gt[512];
                unsigned u2 = gt[1024];
                float2 al = *(const float2*)&sc[(kh * 16 + tpi) * 2];
                p0 += blo(u0) * al.x + bhi(u0) * al.y;
                p1 += blo(u1) * al.x + bhi(u1) * al.y;
                p2 += blo(u2) * al.x + bhi(u2) * al.y;
            }
            red3[kh * 512 + j]       = p0;
            red3[(2 + kh) * 512 + j] = p1;
            red3[(4 + kh) * 512 + j] = p2;
        }
        __syncthreads();

        // ---- gate math -> hm (+ hi/lo pack for next step's GEMV1)
        if (tid < 512) {
            const size_t m = (size_t)k * 128 + b;
            float gi = red3[tid]        + red3[512 + tid]
                     + ntload(&pre_m_h[(m * 3 + 0) * 512 + tid]);
            float gg = red3[1024 + tid] + red3[1536 + tid]
                     + ntload(&pre_m_h[(m * 3 + 1) * 512 + tid]);
            float go = red3[2048 + tid] + red3[2560 + tid]
                     + ntload(&pre_m_h[(m * 3 + 2) * 512 + tid]);
            float cc = fast_sigmoid(gi) * fast_tanh(gg);
            float hv = fast_sigmoid(go) * fast_tanh(cc);
            hm[tid] = hv;
            unsigned hb = f2bf(hv);
            hmh[tid] = (unsigned short)hb;
            hml[tid] = (unsigned short)f2bf(hv - blo(hb));
        }
        __syncthreads();
    }

    if (wv < 3) {
        float p = 0.0f;
#pragma unroll
        for (int u = 0; u < 8; ++u) {
            int h = lane + 64 * u;
            p += hm[h] * fc_w[wv * 512 + h];
        }
#pragma unroll
        for (int off = 32; off; off >>= 1) p += __shfl_xor(p, off);
        if (lane == 0) out[b * 3 + wv] = p + fc_b[wv];
    }
}

extern "C" void kernel_launch(void* const* d_in, const int* in_sizes, int n_in,
                              void* d_out, int out_size, void* d_ws, size_t ws_size,
                              hipStream_t stream)
{
    (void)in_sizes; (void)n_in; (void)out_size;
    const int*   premise    = (const int*)d_in[0];
    const int*   hypothesis = (const int*)d_in[2];
    const float* embed  = (const float*)d_in[4];
    const float* w_e    = (const float*)d_in[5];
    const float* Ws     = (const float*)d_in[6];
    const float* Wt     = (const float*)d_in[7];
    const float* Wm     = (const float*)d_in[8];
    const float* Wih_p  = (const float*)d_in[9];
    const float* bih_p  = (const float*)d_in[10];
    const float* bhh_p  = (const float*)d_in[11];
    const float* Wih_h  = (const float*)d_in[12];
    const float* bih_h  = (const float*)d_in[13];
    const float* bhh_h  = (const float*)d_in[14];
    const float* Wih_m  = (const float*)d_in[15];
    const float* bih_m  = (const float*)d_in[16];
    const float* bhh_m  = (const float*)d_in[17];
    const float* fc_w   = (const float*)d_in[18];
    const float* fc_b   = (const float*)d_in[19];

    // Workspace layout (floats), total 29,360,128 <= guard:
    //   Rh      @ 0         : 2,097,152  (half-scratch; WmB aliases)
    //   pre_s   @ 2,097,152 : 4,194,304
    //   pre_t   @ 6,291,456 : 4,194,304
    //   pre_m_h @10,485,760 :12,582,912  (halves also = encoder preact P)
    //   G3      @23,068,672 : 6,291,456  (bf16 pairs, block-contiguous)
    float* ws      = (float*)d_ws;
    float* Rh      = ws;
    float* pre_s   = ws + 2097152;
    float* pre_t   = ws + 6291456;
    float* pre_m_h = ws + 10485760;
    unsigned* G3u  = (unsigned*)(ws + 23068672);
    unsigned short* G3s = (unsigned short*)G3u;
    unsigned* WmB  = (unsigned*)Rh;           // aliases Rh after last reader
    float* outp    = (float*)d_out;
    if (ws_size < (size_t)29556736 * 4) return;

    dim3 blk(256);

    // ---- Phase A: premise halves -> h_s(half) -> pre_s(half), G3(half)
    for (int h = 0; h < 2; ++h) {
        float* P = pre_m_h + (size_t)h * 6291456;
        mfma_g3_kernel<1><<<dim3(64, 24), blk, 0, stream>>>(
            embed, premise + h * 4096, 300, 300, Wih_p, 300, bih_p, bhh_p, P);
        enc_gates_kernel<<<2048, blk, 0, stream>>>(P, Rh);
        mfma_nt_kernel<<<dim3(64, 8), blk, 0, stream>>>(
            Rh, Ws, pre_s + (size_t)h * 2097152);
        g3pack_kernel<<<dim3(64, 24), blk, 0, stream>>>(
            Rh, Wih_m, G3s, h * 4096);
    }
    // ---- Phase A: hypothesis halves -> h_t(half) -> pre_t(half), pre_m_h(half)
    for (int h = 0; h < 2; ++h) {
        float* P = pre_m_h + (size_t)h * 6291456;
        mfma_g3_kernel<1><<<dim3(64, 24), blk, 0, stream>>>(
            embed, hypothesis + h * 4096, 300, 300, Wih_h, 300, bih_h, bhh_h, P);
        enc_gates_kernel<<<2048, blk, 0, stream>>>(P, Rh);
        mfma_nt_kernel<<<dim3(64, 8), blk, 0, stream>>>(
            Rh, Wt, pre_t + (size_t)h * 2097152);
        mfma_g3_kernel<0><<<dim3(64, 24), blk, 0, stream>>>(
            Rh, nullptr, 512, 512, Wih_m + 512, 1024, bih_m, bhh_m,
            pre_m_h + (size_t)h * 6291456);
    }

    // ---- Wm pack (after Rh's last reader; output aliases Rh)
    pack_wm_kernel<<<512, blk, 0, stream>>>(Wm, WmB);

    // ---- Phase B (128KB dynamic LDS for pre_s cache)
    static int attr_done = 0;
    if (!attr_done) {
        hipFuncSetAttribute((const void*)phaseB_kernel,
                            hipFuncAttributeMaxDynamicSharedMemorySize, 131072);
        attr_done = 1;
    }
    phaseB_kernel<<<dim3(128), dim3(1024), 131072, stream>>>(
        pre_s, pre_t, pre_m_h, WmB, G3u, w_e, fc_w, fc_b, outp);
}

// Round 9
// 1848.102 us; speedup vs baseline: 1.0042x; 1.0042x over previous
//
#include <hip/hip_runtime.h>

// MatchLSTM forward (Round 24): G3 set-ALIGNMENT fix (R23 post-mortem).
//   R23's block-contiguous G3 made FETCH worse (330->735MB): region=192KB
//   -> same-XCD block stride 8x192KB = 1536KB === 0 mod 256KB (L2 set
//   period) -> all 16 co-XCD windows start at the SAME set offset ->
//   sets 0..1535 need 16 G3 ways + Wm + streams > 16-way -> thrash.
//   R24: pad region to 194KB. 8x194 = 1552 === 16KB mod 256KB -> windows
//   at set offsets 0,16,...,240KB (distinct, uniform); avg 12 G3 ways/set.
//   Two-line change (pack idx + phaseB base); numerics identical.
// Everything else: R23 verbatim (validated; absmax 9.77e-4).

#define DEV static __device__ __forceinline__

DEV float fast_sigmoid(float x) { return 1.0f / (1.0f + __expf(-x)); }
DEV float fast_tanh(float x)    { return 1.0f - 2.0f / (__expf(2.0f * x) + 1.0f); }

DEV unsigned f2bf(float x) {
    unsigned v = __float_as_uint(x);
    return (v + 0x7FFFu + ((v >> 16) & 1u)) >> 16;
}
DEV float blo(unsigned u) { return __uint_as_float(u << 16); }
DEV float bhi(unsigned u) { return __uint_as_float(u & 0xFFFF0000u); }

DEV float ntload(const float* p) { return __builtin_nontemporal_load(p); }

typedef __attribute__((ext_vector_type(8))) short bfrag;   // 8 bf16
typedef __attribute__((ext_vector_type(4))) float ffrag;   // 4 fp32 acc

// G3 block region: 32*1536 uints data + 512 uints pad = 49664 uints = 194KB
#define G3_BLK_U 49664

DEV void cvt_hilo(const float* v, bfrag& hi, bfrag& lo)
{
#pragma unroll
    for (int z = 0; z < 8; ++z) {
        unsigned h = f2bf(v[z]);
        hi[z] = (short)h;
        lo[z] = (short)f2bf(v[z] - __uint_as_float(h << 16));
    }
}

// ---------------------------------------------------------------------------
// MFMA GEMM (validated R14): C[M][512] = A[M][512] . W[512][512]^T, bf16x3.
// ---------------------------------------------------------------------------
__global__ __launch_bounds__(256) void mfma_nt_kernel(
    const float* __restrict__ A, const float* __restrict__ W,
    float* __restrict__ C)
{
    const int wv   = threadIdx.x >> 6;
    const int lane = threadIdx.x & 63;
    const int row  = lane & 15;
    const int quad = lane >> 4;
    const int m0 = blockIdx.x * 64 + wv * 16;
    const int n0 = blockIdx.y * 64;

    ffrag acc[4];
#pragma unroll
    for (int n = 0; n < 4; ++n)
#pragma unroll
        for (int r = 0; r < 4; ++r) acc[n][r] = 0.0f;

    for (int k0 = 0; k0 < 512; k0 += 32) {
        const float* ap = A + (size_t)(m0 + row) * 512 + k0 + quad * 8;
        float4 aA = *(const float4*)ap;
        float4 aB = *(const float4*)(ap + 4);
        float av[8] = {aA.x, aA.y, aA.z, aA.w, aB.x, aB.y, aB.z, aB.w};
        bfrag ahi, alo;
        cvt_hilo(av, ahi, alo);
#pragma unroll
        for (int n = 0; n < 4; ++n) {
            const float* wp = W + (size_t)(n0 + n * 16 + row) * 512 + k0 + quad * 8;
            float4 wA = *(const float4*)wp;
            float4 wB = *(const float4*)(wp + 4);
            float wvv[8] = {wA.x, wA.y, wA.z, wA.w, wB.x, wB.y, wB.z, wB.w};
            bfrag whi, wlo;
            cvt_hilo(wvv, whi, wlo);
            acc[n] = __builtin_amdgcn_mfma_f32_16x16x32_bf16(ahi, whi, acc[n], 0, 0, 0);
            acc[n] = __builtin_amdgcn_mfma_f32_16x16x32_bf16(alo, whi, acc[n], 0, 0, 0);
            acc[n] = __builtin_amdgcn_mfma_f32_16x16x32_bf16(ahi, wlo, acc[n], 0, 0, 0);
        }
    }
#pragma unroll
    for (int n = 0; n < 4; ++n)
#pragma unroll
        for (int r = 0; r < 4; ++r)
            C[(size_t)(m0 + quad * 4 + r) * 512 + n0 + n * 16 + row] = acc[n][r];
}

// ---------------------------------------------------------------------------
// 3-gate MFMA GEMM (validated R15): fp32 out + biases.
// ---------------------------------------------------------------------------
template<int GATHER>
__global__ __launch_bounds__(256) void mfma_g3_kernel(
    const float* __restrict__ A, const int* __restrict__ gidx,
    int lda, int K,
    const float* __restrict__ W, int ldw,
    const float* __restrict__ bias1, const float* __restrict__ bias2,
    float* __restrict__ out)
{
    const int wv   = threadIdx.x >> 6;
    const int lane = threadIdx.x & 63;
    const int row  = lane & 15;
    const int quad = lane >> 4;
    const int m0   = blockIdx.x * 64 + wv * 16;
    const int gate = blockIdx.y >> 3;
    const int gbase = (gate == 0) ? 0 : (gate == 1 ? 1024 : 1536);
    const int j0   = (blockIdx.y & 7) * 64;

    const int arow = GATHER ? gidx[m0 + row] : (m0 + row);

    ffrag acc[4];
#pragma unroll
    for (int n = 0; n < 4; ++n)
#pragma unroll
        for (int r = 0; r < 4; ++r) acc[n][r] = 0.0f;

    for (int k0 = 0; k0 < K; k0 += 32) {
        const bool tail = (k0 + 32 > K);
        float av[8];
        if (!tail) {
            const float* ap = A + (size_t)arow * lda + k0 + quad * 8;
            float4 aA = *(const float4*)ap;
            float4 aB = *(const float4*)(ap + 4);
            av[0]=aA.x; av[1]=aA.y; av[2]=aA.z; av[3]=aA.w;
            av[4]=aB.x; av[5]=aB.y; av[6]=aB.z; av[7]=aB.w;
        } else {
#pragma unroll
            for (int z = 0; z < 8; ++z) {
                int kk = k0 + quad * 8 + z;
                av[z] = (kk < K) ? A[(size_t)arow * lda + kk] : 0.0f;
            }
        }
        bfrag ahi, alo;
        cvt_hilo(av, ahi, alo);
#pragma unroll
        for (int n = 0; n < 4; ++n) {
            const int wrow = gbase + j0 + n * 16 + row;
            float wvv[8];
            if (!tail) {
                const float* wp = W + (size_t)wrow * ldw + k0 + quad * 8;
                float4 wA = *(const float4*)wp;
                float4 wB = *(const float4*)(wp + 4);
                wvv[0]=wA.x; wvv[1]=wA.y; wvv[2]=wA.z; wvv[3]=wA.w;
                wvv[4]=wB.x; wvv[5]=wB.y; wvv[6]=wB.z; wvv[7]=wB.w;
            } else {
#pragma unroll
                for (int z = 0; z < 8; ++z) {
                    int kk = k0 + quad * 8 + z;
                    wvv[z] = (kk < K) ? W[(size_t)wrow * ldw + kk] : 0.0f;
                }
            }
            bfrag whi, wlo;
            cvt_hilo(wvv, whi, wlo);
            acc[n] = __builtin_amdgcn_mfma_f32_16x16x32_bf16(ahi, whi, acc[n], 0, 0, 0);
            acc[n] = __builtin_amdgcn_mfma_f32_16x16x32_bf16(alo, whi, acc[n], 0, 0, 0);
            acc[n] = __builtin_amdgcn_mfma_f32_16x16x32_bf16(ahi, wlo, acc[n], 0, 0, 0);
        }
    }
#pragma unroll
    for (int n = 0; n < 4; ++n) {
        const int j = j0 + n * 16 + row;
        const float bb = bias1[gbase + j] + bias2[gbase + j];
#pragma unroll
        for (int r = 0; r < 4; ++r) {
            const int m = m0 + quad * 4 + r;
            out[((size_t)m * 3 + gate) * 512 + j] = acc[n][r] + bb;
        }
    }
}

// ---------------------------------------------------------------------------
// G3 GEMM (R24): block-contiguous + 2KB/block pad (set-offset stagger).
//   ushort idx = b*2*G3_BLK_U + ((tp*1536 + gate*512 + j)*2 + parity)
// ---------------------------------------------------------------------------
__global__ __launch_bounds__(256) void g3pack_kernel(
    const float* __restrict__ A,            // Rh: 4096 x 512
    const float* __restrict__ W,            // Wih_m, ldw 1024
    unsigned short* __restrict__ G3s,
    int mbase)                              // 0 or 4096
{
    const int wv   = threadIdx.x >> 6;
    const int lane = threadIdx.x & 63;
    const int row  = lane & 15;
    const int quad = lane >> 4;
    const int m0   = blockIdx.x * 64 + wv * 16;
    const int gate = blockIdx.y >> 3;
    const int gbase = (gate == 0) ? 0 : (gate == 1 ? 1024 : 1536);
    const int j0   = (blockIdx.y & 7) * 64;

    ffrag acc[4];
#pragma unroll
    for (int n = 0; n < 4; ++n)
#pragma unroll
        for (int r = 0; r < 4; ++r) acc[n][r] = 0.0f;

    for (int k0 = 0; k0 < 512; k0 += 32) {
        const float* ap = A + (size_t)(m0 + row) * 512 + k0 + quad * 8;
        float4 aA = *(const float4*)ap;
        float4 aB = *(const float4*)(ap + 4);
        float av[8] = {aA.x, aA.y, aA.z, aA.w, aB.x, aB.y, aB.z, aB.w};
        bfrag ahi, alo;
        cvt_hilo(av, ahi, alo);
#pragma unroll
        for (int n = 0; n < 4; ++n) {
            const int wrow = gbase + j0 + n * 16 + row;
            const float* wp = W + (size_t)wrow * 1024 + k0 + quad * 8;
            float4 wA = *(const float4*)wp;
            float4 wB = *(const float4*)(wp + 4);
            float wvv[8] = {wA.x, wA.y, wA.z, wA.w, wB.x, wB.y, wB.z, wB.w};
            bfrag whi, wlo;
            cvt_hilo(wvv, whi, wlo);
            acc[n] = __builtin_amdgcn_mfma_f32_16x16x32_bf16(ahi, whi, acc[n], 0, 0, 0);
            acc[n] = __builtin_amdgcn_mfma_f32_16x16x32_bf16(alo, whi, acc[n], 0, 0, 0);
            acc[n] = __builtin_amdgcn_mfma_f32_16x16x32_bf16(ahi, wlo, acc[n], 0, 0, 0);
        }
    }
#pragma unroll
    for (int n = 0; n < 4; ++n) {
        const int j = j0 + n * 16 + row;
#pragma unroll
        for (int r = 0; r < 4; ++r) {
            const int mg = mbase + m0 + quad * 4 + r;
            const int t = mg >> 7, b = mg & 127;
            size_t idx = (size_t)b * (2 * G3_BLK_U)
                       + ((size_t)(t >> 1) * 1536 + gate * 512 + j) * 2
                       + (t & 1);
            G3s[idx] = (unsigned short)f2bf(acc[n][r]);
        }
    }
}

// ---------------------------------------------------------------------------
// Encoder gate math (validated R15).
// ---------------------------------------------------------------------------
__global__ __launch_bounds__(256) void enc_gates_kernel(
    const float* __restrict__ P, float* __restrict__ h)
{
    const int i = blockIdx.x * 256 + threadIdx.x;
    const int m = i >> 7;
    const int j4 = (i & 127) * 4;
    const float* p = P + (size_t)m * 1536 + j4;
    float4 gi = *(const float4*)p;
    float4 gg = *(const float4*)(p + 512);
    float4 go = *(const float4*)(p + 1024);
    float4 r;
    r.x = fast_sigmoid(go.x) * fast_tanh(fast_sigmoid(gi.x) * fast_tanh(gg.x));
    r.y = fast_sigmoid(go.y) * fast_tanh(fast_sigmoid(gi.y) * fast_tanh(gg.y));
    r.z = fast_sigmoid(go.z) * fast_tanh(fast_sigmoid(gi.z) * fast_tanh(gg.z));
    r.w = fast_sigmoid(go.w) * fast_tanh(fast_sigmoid(gi.w) * fast_tanh(gg.w));
    *(float4*)&h[(size_t)m * 512 + j4] = r;
}

// ---------------------------------------------------------------------------
// Wm pack (validated R19): [kc][nt][lane] tile-interleaved.
// ---------------------------------------------------------------------------
__global__ __launch_bounds__(256) void pack_wm_kernel(
    const float* __restrict__ Wm, unsigned* __restrict__ WmB)
{
    int i = blockIdx.x * 256 + threadIdx.x;           // 0 .. 131071
    int u = i & 3, lane = (i >> 2) & 63;
    int nt = (i >> 8) & 31, kc = i >> 13;
    int row = nt * 16 + (lane & 15);
    int k = kc * 32 + ((lane >> 4) << 3) + u * 2;
    unsigned lo = f2bf(Wm[(size_t)row * 512 + k]);
    unsigned hi = f2bf(Wm[(size_t)row * 512 + k + 1]);
    WmB[i] = lo | (hi << 16);
}

// ---------------------------------------------------------------------------
// Phase B (Round 24): R23 + padded G3 base.
// ---------------------------------------------------------------------------
__global__ __launch_bounds__(1024) void phaseB_kernel(
    const float* __restrict__ pre_s, const float* __restrict__ pre_t,
    const float* __restrict__ pre_m_h,
    const unsigned* __restrict__ WmB, const unsigned* __restrict__ G3u,
    const float* __restrict__ w_e,
    const float* __restrict__ fc_w,  const float* __restrict__ fc_b,
    float* __restrict__ out)
{
    extern __shared__ __align__(16) float psL[];      // 64*512 fp32 = 128KB
    __shared__ __align__(16) float hm[512];
    __shared__ __align__(16) float base[512];
    __shared__ __align__(16) float wesh[512];
    __shared__ __align__(16) float sc[64];
    __shared__ __align__(16) float red3[3 * 2 * 512];
    __shared__ __align__(16) unsigned short hmh[512];
    __shared__ __align__(16) unsigned short hml[512];

    const int b    = blockIdx.x;
    const int tid  = threadIdx.x;
    const int wv   = tid >> 6;
    const int lane = tid & 63;
    const int j    = tid & 511;
    const int kh   = tid >> 9;
    const int quad = lane >> 4;

    if (tid < 512) {
        wesh[tid] = w_e[tid];
        hm[tid] = 0.0f; hmh[tid] = 0; hml[tid] = 0;
    }
    // pre_s[t,b,:] -> LDS once (exact fp32), reused all 64 steps
    for (int i = tid; i < 32768; i += 1024) {
        int t = i >> 9, h = i & 511;
        psL[i] = ntload(&pre_s[((size_t)t * 128 + b) * 512 + h]);
    }
    __syncthreads();

    for (int k = 0; k < 64; ++k) {
        // ---- GEMV1 (K-split): partials for base = Wm . hm
        {
            const int kh2 = wv >> 3;               // K-half 0/1
            const int tp  = (wv & 7) * 4;          // 4 tiles per wave
            ffrag a0 = {0.0f,0.0f,0.0f,0.0f}, a1 = {0.0f,0.0f,0.0f,0.0f};
            ffrag a2 = {0.0f,0.0f,0.0f,0.0f}, a3 = {0.0f,0.0f,0.0f,0.0f};
            const uint4* wp = (const uint4*)WmB
                            + ((size_t)(kh2 * 8) * 32 + tp) * 64 + lane;
            const unsigned short* ab = ((lane & 8) == 0) ? hmh : hml;
#pragma unroll 1
            for (int kc = 0; kc < 8; ++kc) {
                bfrag a  = *(const bfrag*)&ab[(kh2 * 8 + kc) * 32 + quad * 8];
                bfrag w0 = *(const bfrag*)(wp);
                bfrag w1 = *(const bfrag*)(wp + 64);
                bfrag w2 = *(const bfrag*)(wp + 128);
                bfrag w3 = *(const bfrag*)(wp + 192);
                a0 = __builtin_amdgcn_mfma_f32_16x16x32_bf16(a, w0, a0, 0, 0, 0);
                a1 = __builtin_amdgcn_mfma_f32_16x16x32_bf16(a, w1, a1, 0, 0, 0);
                a2 = __builtin_amdgcn_mfma_f32_16x16x32_bf16(a, w2, a2, 0, 0, 0);
                a3 = __builtin_amdgcn_mfma_f32_16x16x32_bf16(a, w3, a3, 0, 0, 0);
                wp += 2048;                        // next kc (32 tiles * 64)
            }
            float s0 = a0[0] + __shfl_xor(a0[0], 32);
            float s1 = a1[0] + __shfl_xor(a1[0], 32);
            float s2 = a2[0] + __shfl_xor(a2[0], 32);
            float s3 = a3[0] + __shfl_xor(a3[0], 32);
            if (lane < 16) {
                float* rr = &red3[kh2 * 512];
                rr[(tp + 0) * 16 + lane] = s0;
                rr[(tp + 1) * 16 + lane] = s1;
                rr[(tp + 2) * 16 + lane] = s2;
                rr[(tp + 3) * 16 + lane] = s3;
            }
        }
        __syncthreads();
        if (tid < 512)
            base[tid] = red3[tid] + red3[512 + tid]
                      + ntload(&pre_t[((size_t)k * 128 + b) * 512 + tid]);
        __syncthreads();

        // ---- attention scores: e[t] = w_e . tanh(psL[t] + base)  (all LDS)
#pragma unroll
        for (int tt = 0; tt < 4; ++tt) {
            int t = wv * 4 + tt;
            const float* ps = &psL[t * 512];
            float p = 0.0f;
#pragma unroll
            for (int u = 0; u < 8; ++u) {
                int h = lane + 64 * u;
                p += wesh[h] * fast_tanh(ps[h] + base[h]);
            }
#pragma unroll
            for (int off = 32; off; off >>= 1) p += __shfl_xor(p, off);
            if (lane == 0) sc[t] = p;
        }
        __syncthreads();

        // ---- softmax over 64 premise positions
        if (wv == 0) {
            float s = sc[lane], mx = s;
#pragma unroll
            for (int off = 32; off; off >>= 1) mx = fmaxf(mx, __shfl_xor(mx, off));
            float e = __expf(s - mx), sum = e;
#pragma unroll
            for (int off = 32; off; off >>= 1) sum += __shfl_xor(sum, off);
            sc[lane] = e / sum;
        }
        __syncthreads();

        // ---- gates partials = sum_t alpha_t * G3[t,b,:]  (padded base)
        {
            const unsigned* gb = G3u + (size_t)b * G3_BLK_U + (kh * 16) * 1536 + j;
            float p0 = 0.0f, p1 = 0.0f, p2 = 0.0f;
#pragma unroll 4
            for (int tpi = 0; tpi < 16; ++tpi) {
                const unsigned* gt = gb + (size_t)tpi * 1536;
                unsigned u0 = gt[0];
                unsigned u1 = gt[512];
                unsigned u2 = gt[1024];
                float2 al = *(const float2*)&sc[(kh * 16 + tpi) * 2];
                p0 += blo(u0) * al.x + bhi(u0) * al.y;
                p1 += blo(u1) * al.x + bhi(u1) * al.y;
                p2 += blo(u2) * al.x + bhi(u2) * al.y;
            }
            red3[kh * 512 + j]       = p0;
            red3[(2 + kh) * 512 + j] = p1;
            red3[(4 + kh) * 512 + j] = p2;
        }
        __syncthreads();

        // ---- gate math -> hm (+ hi/lo pack for next step's GEMV1)
        if (tid < 512) {
            const size_t m = (size_t)k * 128 + b;
            float gi = red3[tid]        + red3[512 + tid]
                     + ntload(&pre_m_h[(m * 3 + 0) * 512 + tid]);
            float gg = red3[1024 + tid] + red3[1536 + tid]
                     + ntload(&pre_m_h[(m * 3 + 1) * 512 + tid]);
            float go = red3[2048 + tid] + red3[2560 + tid]
                     + ntload(&pre_m_h[(m * 3 + 2) * 512 + tid]);
            float cc = fast_sigmoid(gi) * fast_tanh(gg);
            float hv = fast_sigmoid(go) * fast_tanh(cc);
            hm[tid] = hv;
            unsigned hb = f2bf(hv);
            hmh[tid] = (unsigned short)hb;
            hml[tid] = (unsigned short)f2bf(hv - blo(hb));
        }
        __syncthreads();
    }

    if (wv < 3) {
        float p = 0.0f;
#pragma unroll
        for (int u = 0; u < 8; ++u) {
            int h = lane + 64 * u;
            p += hm[h] * fc_w[wv * 512 + h];
        }
#pragma unroll
        for (int off = 32; off; off >>= 1) p += __shfl_xor(p, off);
        if (lane == 0) out[b * 3 + wv] = p + fc_b[wv];
    }
}

extern "C" void kernel_launch(void* const* d_in, const int* in_sizes, int n_in,
                              void* d_out, int out_size, void* d_ws, size_t ws_size,
                              hipStream_t stream)
{
    (void)in_sizes; (void)n_in; (void)out_size;
    const int*   premise    = (const int*)d_in[0];
    const int*   hypothesis = (const int*)d_in[2];
    const float* embed  = (const float*)d_in[4];
    const float* w_e    = (const float*)d_in[5];
    const float* Ws     = (const float*)d_in[6];
    const float* Wt     = (const float*)d_in[7];
    const float* Wm     = (const float*)d_in[8];
    const float* Wih_p  = (const float*)d_in[9];
    const float* bih_p  = (const float*)d_in[10];
    const float* bhh_p  = (const float*)d_in[11];
    const float* Wih_h  = (const float*)d_in[12];
    const float* bih_h  = (const float*)d_in[13];
    const float* bhh_h  = (const float*)d_in[14];
    const float* Wih_m  = (const float*)d_in[15];
    const float* bih_m  = (const float*)d_in[16];
    const float* bhh_m  = (const float*)d_in[17];
    const float* fc_w   = (const float*)d_in[18];
    const float* fc_b   = (const float*)d_in[19];

    // Workspace layout (floats), total 29,425,664 <= guard 29,556,736:
    //   Rh      @ 0         : 2,097,152  (half-scratch; WmB aliases)
    //   pre_s   @ 2,097,152 : 4,194,304
    //   pre_t   @ 6,291,456 : 4,194,304
    //   pre_m_h @10,485,760 :12,582,912  (halves also = encoder preact P)
    //   G3      @23,068,672 : 6,356,992  (bf16 pairs, 194KB/block padded)
    float* ws      = (float*)d_ws;
    float* Rh      = ws;
    float* pre_s   = ws + 2097152;
    float* pre_t   = ws + 6291456;
    float* pre_m_h = ws + 10485760;
    unsigned* G3u  = (unsigned*)(ws + 23068672);
    unsigned short* G3s = (unsigned short*)G3u;
    unsigned* WmB  = (unsigned*)Rh;           // aliases Rh after last reader
    float* outp    = (float*)d_out;
    if (ws_size < (size_t)29556736 * 4) return;

    dim3 blk(256);

    // ---- Phase A: premise halves -> h_s(half) -> pre_s(half), G3(half)
    for (int h = 0; h < 2; ++h) {
        float* P = pre_m_h + (size_t)h * 6291456;
        mfma_g3_kernel<1><<<dim3(64, 24), blk, 0, stream>>>(
            embed, premise + h * 4096, 300, 300, Wih_p, 300, bih_p, bhh_p, P);
        enc_gates_kernel<<<2048, blk, 0, stream>>>(P, Rh);
        mfma_nt_kernel<<<dim3(64, 8), blk, 0, stream>>>(
            Rh, Ws, pre_s + (size_t)h * 2097152);
        g3pack_kernel<<<dim3(64, 24), blk, 0, stream>>>(
            Rh, Wih_m, G3s, h * 4096);
    }
    // ---- Phase A: hypothesis halves -> h_t(half) -> pre_t(half), pre_m_h(half)
    for (int h = 0; h < 2; ++h) {
        float* P = pre_m_h + (size_t)h * 6291456;
        mfma_g3_kernel<1><<<dim3(64, 24), blk, 0, stream>>>(
            embed, hypothesis + h * 4096, 300, 300, Wih_h, 300, bih_h, bhh_h, P);
        enc_gates_kernel<<<2048, blk, 0, stream>>>(P, Rh);
        mfma_nt_kernel<<<dim3(64, 8), blk, 0, stream>>>(
            Rh, Wt, pre_t + (size_t)h * 2097152);
        mfma_g3_kernel<0><<<dim3(64, 24), blk, 0, stream>>>(
            Rh, nullptr, 512, 512, Wih_m + 512, 1024, bih_m, bhh_m,
            pre_m_h + (size_t)h * 6291456);
    }

    // ---- Wm pack (after Rh's last reader; output aliases Rh)
    pack_wm_kernel<<<512, blk, 0, stream>>>(Wm, WmB);

    // ---- Phase B (128KB dynamic LDS for pre_s cache)
    static int attr_done = 0;
    if (!attr_done) {
        hipFuncSetAttribute((const void*)phaseB_kernel,
                            hipFuncAttributeMaxDynamicSharedMemorySize, 131072);
        attr_done = 1;
    }
    phaseB_kernel<<<dim3(128), dim3(1024), 131072, stream>>>(
        pre_s, pre_t, pre_m_h, WmB, G3u, w_e, fc_w, fc_b, outp);
}

// Round 10
// 1698.146 us; speedup vs baseline: 1.0929x; 1.0883x over previous
//
#include <hip/hip_runtime.h>

// MatchLSTM forward (Round 25): G3-sum moved to MFMA.
//   R22-R24 lesson: phaseB time invariant to FETCH (905/940/923 us at
//   330/735/550 MB) -> misses latency-hidden, NOT the critical path.
//   Active-CU VALU ~48% busy; G3-sum phase = 48 scalar loads + 96
//   unpack/FMA PER THREAD (~770 issues/wave) with 4-way MLP -> dominant.
//   R25: G3-sum = 1x64 x 64x1536 GEMV -> MFMA. G3 repacked t-major
//   [b][j][t] (same 194KB padded region as R24); alpha in A-rows hi/lo
//   (R19-validated broadcast trick, sch/scl bf16 split ~= fp32). Per wave:
//   12 b128 loads + 12 MFMAs replace ~770 scalar ops. Full K=64 sums ->
//   red3 partial-reduction deleted. GEMV1/attention/phaseA untouched.
//   Tripwire: WRITE_SIZE ~5KB (G3 phase ~60 VGPR at the 64 cap).

#define DEV static __device__ __forceinline__

DEV float fast_sigmoid(float x) { return 1.0f / (1.0f + __expf(-x)); }
DEV float fast_tanh(float x)    { return 1.0f - 2.0f / (__expf(2.0f * x) + 1.0f); }

DEV unsigned f2bf(float x) {
    unsigned v = __float_as_uint(x);
    return (v + 0x7FFFu + ((v >> 16) & 1u)) >> 16;
}
DEV float blo(unsigned u) { return __uint_as_float(u << 16); }

DEV float ntload(const float* p) { return __builtin_nontemporal_load(p); }

typedef __attribute__((ext_vector_type(8))) short bfrag;   // 8 bf16
typedef __attribute__((ext_vector_type(4))) float ffrag;   // 4 fp32 acc

// G3 block region (ushorts): 1536*64 data + 1024 pad = 99328 = 194KB
// (R24-validated stagger: 8 co-XCD blocks land at set offsets 0,16..240KB)
#define G3_BLK_S 99328

DEV void cvt_hilo(const float* v, bfrag& hi, bfrag& lo)
{
#pragma unroll
    for (int z = 0; z < 8; ++z) {
        unsigned h = f2bf(v[z]);
        hi[z] = (short)h;
        lo[z] = (short)f2bf(v[z] - __uint_as_float(h << 16));
    }
}

// ---------------------------------------------------------------------------
// MFMA GEMM (validated R14): C[M][512] = A[M][512] . W[512][512]^T, bf16x3.
// ---------------------------------------------------------------------------
__global__ __launch_bounds__(256) void mfma_nt_kernel(
    const float* __restrict__ A, const float* __restrict__ W,
    float* __restrict__ C)
{
    const int wv   = threadIdx.x >> 6;
    const int lane = threadIdx.x & 63;
    const int row  = lane & 15;
    const int quad = lane >> 4;
    const int m0 = blockIdx.x * 64 + wv * 16;
    const int n0 = blockIdx.y * 64;

    ffrag acc[4];
#pragma unroll
    for (int n = 0; n < 4; ++n)
#pragma unroll
        for (int r = 0; r < 4; ++r) acc[n][r] = 0.0f;

    for (int k0 = 0; k0 < 512; k0 += 32) {
        const float* ap = A + (size_t)(m0 + row) * 512 + k0 + quad * 8;
        float4 aA = *(const float4*)ap;
        float4 aB = *(const float4*)(ap + 4);
        float av[8] = {aA.x, aA.y, aA.z, aA.w, aB.x, aB.y, aB.z, aB.w};
        bfrag ahi, alo;
        cvt_hilo(av, ahi, alo);
#pragma unroll
        for (int n = 0; n < 4; ++n) {
            const float* wp = W + (size_t)(n0 + n * 16 + row) * 512 + k0 + quad * 8;
            float4 wA = *(const float4*)wp;
            float4 wB = *(const float4*)(wp + 4);
            float wvv[8] = {wA.x, wA.y, wA.z, wA.w, wB.x, wB.y, wB.z, wB.w};
            bfrag whi, wlo;
            cvt_hilo(wvv, whi, wlo);
            acc[n] = __builtin_amdgcn_mfma_f32_16x16x32_bf16(ahi, whi, acc[n], 0, 0, 0);
            acc[n] = __builtin_amdgcn_mfma_f32_16x16x32_bf16(alo, whi, acc[n], 0, 0, 0);
            acc[n] = __builtin_amdgcn_mfma_f32_16x16x32_bf16(ahi, wlo, acc[n], 0, 0, 0);
        }
    }
#pragma unroll
    for (int n = 0; n < 4; ++n)
#pragma unroll
        for (int r = 0; r < 4; ++r)
            C[(size_t)(m0 + quad * 4 + r) * 512 + n0 + n * 16 + row] = acc[n][r];
}

// ---------------------------------------------------------------------------
// 3-gate MFMA GEMM (validated R15): fp32 out + biases.
// ---------------------------------------------------------------------------
template<int GATHER>
__global__ __launch_bounds__(256) void mfma_g3_kernel(
    const float* __restrict__ A, const int* __restrict__ gidx,
    int lda, int K,
    const float* __restrict__ W, int ldw,
    const float* __restrict__ bias1, const float* __restrict__ bias2,
    float* __restrict__ out)
{
    const int wv   = threadIdx.x >> 6;
    const int lane = threadIdx.x & 63;
    const int row  = lane & 15;
    const int quad = lane >> 4;
    const int m0   = blockIdx.x * 64 + wv * 16;
    const int gate = blockIdx.y >> 3;
    const int gbase = (gate == 0) ? 0 : (gate == 1 ? 1024 : 1536);
    const int j0   = (blockIdx.y & 7) * 64;

    const int arow = GATHER ? gidx[m0 + row] : (m0 + row);

    ffrag acc[4];
#pragma unroll
    for (int n = 0; n < 4; ++n)
#pragma unroll
        for (int r = 0; r < 4; ++r) acc[n][r] = 0.0f;

    for (int k0 = 0; k0 < K; k0 += 32) {
        const bool tail = (k0 + 32 > K);
        float av[8];
        if (!tail) {
            const float* ap = A + (size_t)arow * lda + k0 + quad * 8;
            float4 aA = *(const float4*)ap;
            float4 aB = *(const float4*)(ap + 4);
            av[0]=aA.x; av[1]=aA.y; av[2]=aA.z; av[3]=aA.w;
            av[4]=aB.x; av[5]=aB.y; av[6]=aB.z; av[7]=aB.w;
        } else {
#pragma unroll
            for (int z = 0; z < 8; ++z) {
                int kk = k0 + quad * 8 + z;
                av[z] = (kk < K) ? A[(size_t)arow * lda + kk] : 0.0f;
            }
        }
        bfrag ahi, alo;
        cvt_hilo(av, ahi, alo);
#pragma unroll
        for (int n = 0; n < 4; ++n) {
            const int wrow = gbase + j0 + n * 16 + row;
            float wvv[8];
            if (!tail) {
                const float* wp = W + (size_t)wrow * ldw + k0 + quad * 8;
                float4 wA = *(const float4*)wp;
                float4 wB = *(const float4*)(wp + 4);
                wvv[0]=wA.x; wvv[1]=wA.y; wvv[2]=wA.z; wvv[3]=wA.w;
                wvv[4]=wB.x; wvv[5]=wB.y; wvv[6]=wB.z; wvv[7]=wB.w;
            } else {
#pragma unroll
                for (int z = 0; z < 8; ++z) {
                    int kk = k0 + quad * 8 + z;
                    wvv[z] = (kk < K) ? W[(size_t)wrow * ldw + kk] : 0.0f;
                }
            }
            bfrag whi, wlo;
            cvt_hilo(wvv, whi, wlo);
            acc[n] = __builtin_amdgcn_mfma_f32_16x16x32_bf16(ahi, whi, acc[n], 0, 0, 0);
            acc[n] = __builtin_amdgcn_mfma_f32_16x16x32_bf16(alo, whi, acc[n], 0, 0, 0);
            acc[n] = __builtin_amdgcn_mfma_f32_16x16x32_bf16(ahi, wlo, acc[n], 0, 0, 0);
        }
    }
#pragma unroll
    for (int n = 0; n < 4; ++n) {
        const int j = j0 + n * 16 + row;
        const float bb = bias1[gbase + j] + bias2[gbase + j];
#pragma unroll
        for (int r = 0; r < 4; ++r) {
            const int m = m0 + quad * 4 + r;
            out[((size_t)m * 3 + gate) * 512 + j] = acc[n][r] + bb;
        }
    }
}

// ---------------------------------------------------------------------------
// G3 GEMM (R25): t-major pack. G3T[b][gate*512+j][t] = W3 . h_s[t,b,:],
// bf16. Per-block region G3_BLK_S ushorts (194KB, R24 stagger kept).
// ---------------------------------------------------------------------------
__global__ __launch_bounds__(256) void g3pack_kernel(
    const float* __restrict__ A,            // Rh: 4096 x 512
    const float* __restrict__ W,            // Wih_m, ldw 1024
    unsigned short* __restrict__ G3s,
    int mbase)                              // 0 or 4096
{
    const int wv   = threadIdx.x >> 6;
    const int lane = threadIdx.x & 63;
    const int row  = lane & 15;
    const int quad = lane >> 4;
    const int m0   = blockIdx.x * 64 + wv * 16;
    const int gate = blockIdx.y >> 3;
    const int gbase = (gate == 0) ? 0 : (gate == 1 ? 1024 : 1536);
    const int j0   = (blockIdx.y & 7) * 64;

    ffrag acc[4];
#pragma unroll
    for (int n = 0; n < 4; ++n)
#pragma unroll
        for (int r = 0; r < 4; ++r) acc[n][r] = 0.0f;

    for (int k0 = 0; k0 < 512; k0 += 32) {
        const float* ap = A + (size_t)(m0 + row) * 512 + k0 + quad * 8;
        float4 aA = *(const float4*)ap;
        float4 aB = *(const float4*)(ap + 4);
        float av[8] = {aA.x, aA.y, aA.z, aA.w, aB.x, aB.y, aB.z, aB.w};
        bfrag ahi, alo;
        cvt_hilo(av, ahi, alo);
#pragma unroll
        for (int n = 0; n < 4; ++n) {
            const int wrow = gbase + j0 + n * 16 + row;
            const float* wp = W + (size_t)wrow * 1024 + k0 + quad * 8;
            float4 wA = *(const float4*)wp;
            float4 wB = *(const float4*)(wp + 4);
            float wvv[8] = {wA.x, wA.y, wA.z, wA.w, wB.x, wB.y, wB.z, wB.w};
            bfrag whi, wlo;
            cvt_hilo(wvv, whi, wlo);
            acc[n] = __builtin_amdgcn_mfma_f32_16x16x32_bf16(ahi, whi, acc[n], 0, 0, 0);
            acc[n] = __builtin_amdgcn_mfma_f32_16x16x32_bf16(alo, whi, acc[n], 0, 0, 0);
            acc[n] = __builtin_amdgcn_mfma_f32_16x16x32_bf16(ahi, wlo, acc[n], 0, 0, 0);
        }
    }
#pragma unroll
    for (int n = 0; n < 4; ++n) {
        const int j = j0 + n * 16 + row;
#pragma unroll
        for (int r = 0; r < 4; ++r) {
            const int mg = mbase + m0 + quad * 4 + r;
            const int t = mg >> 7, b = mg & 127;
            size_t idx = (size_t)b * G3_BLK_S
                       + ((size_t)(gate * 512 + j)) * 64 + t;
            G3s[idx] = (unsigned short)f2bf(acc[n][r]);
        }
    }
}

// ---------------------------------------------------------------------------
// Encoder gate math (validated R15).
// ---------------------------------------------------------------------------
__global__ __launch_bounds__(256) void enc_gates_kernel(
    const float* __restrict__ P, float* __restrict__ h)
{
    const int i = blockIdx.x * 256 + threadIdx.x;
    const int m = i >> 7;
    const int j4 = (i & 127) * 4;
    const float* p = P + (size_t)m * 1536 + j4;
    float4 gi = *(const float4*)p;
    float4 gg = *(const float4*)(p + 512);
    float4 go = *(const float4*)(p + 1024);
    float4 r;
    r.x = fast_sigmoid(go.x) * fast_tanh(fast_sigmoid(gi.x) * fast_tanh(gg.x));
    r.y = fast_sigmoid(go.y) * fast_tanh(fast_sigmoid(gi.y) * fast_tanh(gg.y));
    r.z = fast_sigmoid(go.z) * fast_tanh(fast_sigmoid(gi.z) * fast_tanh(gg.z));
    r.w = fast_sigmoid(go.w) * fast_tanh(fast_sigmoid(gi.w) * fast_tanh(gg.w));
    *(float4*)&h[(size_t)m * 512 + j4] = r;
}

// ---------------------------------------------------------------------------
// Wm pack (validated R19): [kc][nt][lane] tile-interleaved.
// ---------------------------------------------------------------------------
__global__ __launch_bounds__(256) void pack_wm_kernel(
    const float* __restrict__ Wm, unsigned* __restrict__ WmB)
{
    int i = blockIdx.x * 256 + threadIdx.x;           // 0 .. 131071
    int u = i & 3, lane = (i >> 2) & 63;
    int nt = (i >> 8) & 31, kc = i >> 13;
    int row = nt * 16 + (lane & 15);
    int k = kc * 32 + ((lane >> 4) << 3) + u * 2;
    unsigned lo = f2bf(Wm[(size_t)row * 512 + k]);
    unsigned hi = f2bf(Wm[(size_t)row * 512 + k + 1]);
    WmB[i] = lo | (hi << 16);
}

// ---------------------------------------------------------------------------
// Phase B (Round 25): GEMV1 (R24 verbatim) + MFMA G3-sum (t-major).
// ---------------------------------------------------------------------------
__global__ __launch_bounds__(1024) void phaseB_kernel(
    const float* __restrict__ pre_s, const float* __restrict__ pre_t,
    const float* __restrict__ pre_m_h,
    const unsigned* __restrict__ WmB, const unsigned short* __restrict__ G3s,
    const float* __restrict__ w_e,
    const float* __restrict__ fc_w,  const float* __restrict__ fc_b,
    float* __restrict__ out)
{
    extern __shared__ __align__(16) float psL[];      // 64*512 fp32 = 128KB
    __shared__ __align__(16) float hm[512];
    __shared__ __align__(16) float base[512];
    __shared__ __align__(16) float wesh[512];
    __shared__ __align__(16) float sc[64];
    __shared__ __align__(16) float red[2 * 512];
    __shared__ __align__(16) float gates3[1536];
    __shared__ __align__(16) unsigned short hmh[512];
    __shared__ __align__(16) unsigned short hml[512];
    __shared__ __align__(16) unsigned short sch[64];
    __shared__ __align__(16) unsigned short scl[64];

    const int b    = blockIdx.x;
    const int tid  = threadIdx.x;
    const int wv   = tid >> 6;
    const int lane = tid & 63;
    const int kh   = tid >> 9;
    const int col  = lane & 15;
    const int quad = lane >> 4;

    if (tid < 512) {
        wesh[tid] = w_e[tid];
        hm[tid] = 0.0f; hmh[tid] = 0; hml[tid] = 0;
    }
    // pre_s[t,b,:] -> LDS once (exact fp32), reused all 64 steps
    for (int i = tid; i < 32768; i += 1024) {
        int t = i >> 9, h = i & 511;
        psL[i] = ntload(&pre_s[((size_t)t * 128 + b) * 512 + h]);
    }
    __syncthreads();

    for (int k = 0; k < 64; ++k) {
        // ---- GEMV1 (K-split): partials for base = Wm . hm  (R24 verbatim)
        {
            const int kh2 = wv >> 3;               // K-half 0/1
            const int tp  = (wv & 7) * 4;          // 4 tiles per wave
            ffrag a0 = {0.0f,0.0f,0.0f,0.0f}, a1 = {0.0f,0.0f,0.0f,0.0f};
            ffrag a2 = {0.0f,0.0f,0.0f,0.0f}, a3 = {0.0f,0.0f,0.0f,0.0f};
            const uint4* wp = (const uint4*)WmB
                            + ((size_t)(kh2 * 8) * 32 + tp) * 64 + lane;
            const unsigned short* ab = ((lane & 8) == 0) ? hmh : hml;
#pragma unroll 1
            for (int kc = 0; kc < 8; ++kc) {
                bfrag a  = *(const bfrag*)&ab[(kh2 * 8 + kc) * 32 + quad * 8];
                bfrag w0 = *(const bfrag*)(wp);
                bfrag w1 = *(const bfrag*)(wp + 64);
                bfrag w2 = *(const bfrag*)(wp + 128);
                bfrag w3 = *(const bfrag*)(wp + 192);
                a0 = __builtin_amdgcn_mfma_f32_16x16x32_bf16(a, w0, a0, 0, 0, 0);
                a1 = __builtin_amdgcn_mfma_f32_16x16x32_bf16(a, w1, a1, 0, 0, 0);
                a2 = __builtin_amdgcn_mfma_f32_16x16x32_bf16(a, w2, a2, 0, 0, 0);
                a3 = __builtin_amdgcn_mfma_f32_16x16x32_bf16(a, w3, a3, 0, 0, 0);
                wp += 2048;                        // next kc (32 tiles * 64)
            }
            float s0 = a0[0] + __shfl_xor(a0[0], 32);
            float s1 = a1[0] + __shfl_xor(a1[0], 32);
            float s2 = a2[0] + __shfl_xor(a2[0], 32);
            float s3 = a3[0] + __shfl_xor(a3[0], 32);
            if (lane < 16) {
                float* rr = &red[kh2 * 512];
                rr[(tp + 0) * 16 + lane] = s0;
                rr[(tp + 1) * 16 + lane] = s1;
                rr[(tp + 2) * 16 + lane] = s2;
                rr[(tp + 3) * 16 + lane] = s3;
            }
        }
        __syncthreads();
        if (tid < 512)
            base[tid] = red[tid] + red[512 + tid]
                      + ntload(&pre_t[((size_t)k * 128 + b) * 512 + tid]);
        __syncthreads();

        // ---- attention scores: e[t] = w_e . tanh(psL[t] + base)  (all LDS)
#pragma unroll
        for (int tt = 0; tt < 4; ++tt) {
            int t = wv * 4 + tt;
            const float* ps = &psL[t * 512];
            float p = 0.0f;
#pragma unroll
            for (int u = 0; u < 8; ++u) {
                int h = lane + 64 * u;
                p += wesh[h] * fast_tanh(ps[h] + base[h]);
            }
#pragma unroll
            for (int off = 32; off; off >>= 1) p += __shfl_xor(p, off);
            if (lane == 0) sc[t] = p;
        }
        __syncthreads();

        // ---- softmax over 64 premise positions (+ bf16 hi/lo pack of alpha)
        if (wv == 0) {
            float s = sc[lane], mx = s;
#pragma unroll
            for (int off = 32; off; off >>= 1) mx = fmaxf(mx, __shfl_xor(mx, off));
            float e = __expf(s - mx), sum = e;
#pragma unroll
            for (int off = 32; off; off >>= 1) sum += __shfl_xor(sum, off);
            float a = e / sum;
            unsigned hb = f2bf(a);
            sch[lane] = (unsigned short)hb;
            scl[lane] = (unsigned short)f2bf(a - blo(hb));
        }
        __syncthreads();

        // ---- gates = sum_t alpha_t * G3T[b][:,t]  via MFMA (K=64, 2 steps)
        {
            const unsigned short* ab = ((lane & 8) == 0) ? sch : scl;
            bfrag aA = *(const bfrag*)&ab[quad * 8];          // k = 0..31
            bfrag aB = *(const bfrag*)&ab[32 + quad * 8];     // k = 32..63
            const unsigned short* gp = G3s + (size_t)b * G3_BLK_S
                                     + ((size_t)(wv * 96) + col) * 64 + quad * 8;
            ffrag g[6];
#pragma unroll
            for (int t6 = 0; t6 < 6; ++t6) {
                g[t6][0] = 0.0f; g[t6][1] = 0.0f; g[t6][2] = 0.0f; g[t6][3] = 0.0f;
            }
#pragma unroll
            for (int t6 = 0; t6 < 6; ++t6) {
                bfrag w0 = *(const bfrag*)(gp + t6 * 1024);
                g[t6] = __builtin_amdgcn_mfma_f32_16x16x32_bf16(aA, w0, g[t6], 0, 0, 0);
            }
#pragma unroll
            for (int t6 = 0; t6 < 6; ++t6) {
                bfrag w1 = *(const bfrag*)(gp + t6 * 1024 + 32);
                g[t6] = __builtin_amdgcn_mfma_f32_16x16x32_bf16(aB, w1, g[t6], 0, 0, 0);
            }
#pragma unroll
            for (int t6 = 0; t6 < 6; ++t6) {
                float s = g[t6][0] + __shfl_xor(g[t6][0], 32);
                if (lane < 16) gates3[(wv * 6 + t6) * 16 + lane] = s;
            }
        }
        __syncthreads();

        // ---- gate math -> hm (+ hi/lo pack for next step's GEMV1)
        if (tid < 512) {
            const size_t m = (size_t)k * 128 + b;
            float gi = gates3[tid]        + ntload(&pre_m_h[(m * 3 + 0) * 512 + tid]);
            float gg = gates3[512 + tid]  + ntload(&pre_m_h[(m * 3 + 1) * 512 + tid]);
            float go = gates3[1024 + tid] + ntload(&pre_m_h[(m * 3 + 2) * 512 + tid]);
            float cc = fast_sigmoid(gi) * fast_tanh(gg);
            float hv = fast_sigmoid(go) * fast_tanh(cc);
            hm[tid] = hv;
            unsigned hb = f2bf(hv);
            hmh[tid] = (unsigned short)hb;
            hml[tid] = (unsigned short)f2bf(hv - blo(hb));
        }
        __syncthreads();
    }

    if (wv < 3) {
        float p = 0.0f;
#pragma unroll
        for (int u = 0; u < 8; ++u) {
            int h = lane + 64 * u;
            p += hm[h] * fc_w[wv * 512 + h];
        }
#pragma unroll
        for (int off = 32; off; off >>= 1) p += __shfl_xor(p, off);
        if (lane == 0) out[b * 3 + wv] = p + fc_b[wv];
    }
}

extern "C" void kernel_launch(void* const* d_in, const int* in_sizes, int n_in,
                              void* d_out, int out_size, void* d_ws, size_t ws_size,
                              hipStream_t stream)
{
    (void)in_sizes; (void)n_in; (void)out_size;
    const int*   premise    = (const int*)d_in[0];
    const int*   hypothesis = (const int*)d_in[2];
    const float* embed  = (const float*)d_in[4];
    const float* w_e    = (const float*)d_in[5];
    const float* Ws     = (const float*)d_in[6];
    const float* Wt     = (const float*)d_in[7];
    const float* Wm     = (const float*)d_in[8];
    const float* Wih_p  = (const float*)d_in[9];
    const float* bih_p  = (const float*)d_in[10];
    const float* bhh_p  = (const float*)d_in[11];
    const float* Wih_h  = (const float*)d_in[12];
    const float* bih_h  = (const float*)d_in[13];
    const float* bhh_h  = (const float*)d_in[14];
    const float* Wih_m  = (const float*)d_in[15];
    const float* bih_m  = (const float*)d_in[16];
    const float* bhh_m  = (const float*)d_in[17];
    const float* fc_w   = (const float*)d_in[18];
    const float* fc_b   = (const float*)d_in[19];

    // Workspace layout (floats), total 29,425,664 <= guard 29,556,736:
    //   Rh      @ 0         : 2,097,152  (half-scratch; WmB aliases)
    //   pre_s   @ 2,097,152 : 4,194,304
    //   pre_t   @ 6,291,456 : 4,194,304
    //   pre_m_h @10,485,760 :12,582,912  (halves also = encoder preact P)
    //   G3      @23,068,672 : 6,356,992  (bf16 t-major, 194KB/block padded)
    float* ws      = (float*)d_ws;
    float* Rh      = ws;
    float* pre_s   = ws + 2097152;
    float* pre_t   = ws + 6291456;
    float* pre_m_h = ws + 10485760;
    unsigned short* G3s = (unsigned short*)(ws + 23068672);
    unsigned* WmB  = (unsigned*)Rh;           // aliases Rh after last reader
    float* outp    = (float*)d_out;
    if (ws_size < (size_t)29556736 * 4) return;

    dim3 blk(256);

    // ---- Phase A: premise halves -> h_s(half) -> pre_s(half), G3(half)
    for (int h = 0; h < 2; ++h) {
        float* P = pre_m_h + (size_t)h * 6291456;
        mfma_g3_kernel<1><<<dim3(64, 24), blk, 0, stream>>>(
            embed, premise + h * 4096, 300, 300, Wih_p, 300, bih_p, bhh_p, P);
        enc_gates_kernel<<<2048, blk, 0, stream>>>(P, Rh);
        mfma_nt_kernel<<<dim3(64, 8), blk, 0, stream>>>(
            Rh, Ws, pre_s + (size_t)h * 2097152);
        g3pack_kernel<<<dim3(64, 24), blk, 0, stream>>>(
            Rh, Wih_m, G3s, h * 4096);
    }
    // ---- Phase A: hypothesis halves -> h_t(half) -> pre_t(half), pre_m_h(half)
    for (int h = 0; h < 2; ++h) {
        float* P = pre_m_h + (size_t)h * 6291456;
        mfma_g3_kernel<1><<<dim3(64, 24), blk, 0, stream>>>(
            embed, hypothesis + h * 4096, 300, 300, Wih_h, 300, bih_h, bhh_h, P);
        enc_gates_kernel<<<2048, blk, 0, stream>>>(P, Rh);
        mfma_nt_kernel<<<dim3(64, 8), blk, 0, stream>>>(
            Rh, Wt, pre_t + (size_t)h * 2097152);
        mfma_g3_kernel<0><<<dim3(64, 24), blk, 0, stream>>>(
            Rh, nullptr, 512, 512, Wih_m + 512, 1024, bih_m, bhh_m,
            pre_m_h + (size_t)h * 6291456);
    }

    // ---- Wm pack (after Rh's last reader; output aliases Rh)
    pack_wm_kernel<<<512, blk, 0, stream>>>(Wm, WmB);

    // ---- Phase B (128KB dynamic LDS for pre_s cache)
    static int attr_done = 0;
    if (!attr_done) {
        hipFuncSetAttribute((const void*)phaseB_kernel,
                            hipFuncAttributeMaxDynamicSharedMemorySize, 131072);
        attr_done = 1;
    }
    phaseB_kernel<<<dim3(128), dim3(1024), 131072, stream>>>(
        pre_s, pre_t, pre_m_h, WmB, G3s, w_e, fc_w, fc_b, outp);
}

// Round 11
// 1555.263 us; speedup vs baseline: 1.1933x; 1.0919x over previous
//
#include <hip/hip_runtime.h>

// MatchLSTM forward (Round 26): phase-A MFMA density fix.
//   R25 left phaseB at 760us; phase A (~940us aggregate) is now the larger
//   half. Its GEMMs are VALU-bound: in-loop fp32->bf16 cvt_hilo = ~200 VALU
//   instrs per k0 per wave vs 12 MFMAs (6.7:1). R26: 4 M-TILES PER WAVE
//   (64 rows x 64 cols): per k0 = 4 A-cvts + 4 W-cvts + 48 MFMAs ->
//   VALU/MFMA 16.7 -> 6.7 per MFMA (2.5x density). Per-output MFMA sequence
//   and k-order IDENTICAL -> bit-identical results (absmax must stay
//   0.0009765625 exactly). VGPR ~120 @ launch_bounds(256,2) [128 cap].
//   Grids: (16,24)/(16,8). Tripwire: GEMM WRITE_SIZE (spill detector).
// phaseB + G3 t-major + pads: R25 verbatim (validated).

#define DEV static __device__ __forceinline__

DEV float fast_sigmoid(float x) { return 1.0f / (1.0f + __expf(-x)); }
DEV float fast_tanh(float x)    { return 1.0f - 2.0f / (__expf(2.0f * x) + 1.0f); }

DEV unsigned f2bf(float x) {
    unsigned v = __float_as_uint(x);
    return (v + 0x7FFFu + ((v >> 16) & 1u)) >> 16;
}
DEV float blo(unsigned u) { return __uint_as_float(u << 16); }

DEV float ntload(const float* p) { return __builtin_nontemporal_load(p); }

typedef __attribute__((ext_vector_type(8))) short bfrag;   // 8 bf16
typedef __attribute__((ext_vector_type(4))) float ffrag;   // 4 fp32 acc

// G3 block region (ushorts): 1536*64 data + 1024 pad = 99328 = 194KB
#define G3_BLK_S 99328

DEV void cvt_hilo(const float* v, bfrag& hi, bfrag& lo)
{
#pragma unroll
    for (int z = 0; z < 8; ++z) {
        unsigned h = f2bf(v[z]);
        hi[z] = (short)h;
        lo[z] = (short)f2bf(v[z] - __uint_as_float(h << 16));
    }
}

// ---------------------------------------------------------------------------
// MFMA GEMM (R26: 4 M-tiles/wave): C[M][512] = A[M][512] . W[512][512]^T.
// Wave = 64 M-rows x 64 N-cols. Per-output MFMA order identical to R14.
// ---------------------------------------------------------------------------
__global__ __launch_bounds__(256, 2) void mfma_nt_kernel(
    const float* __restrict__ A, const float* __restrict__ W,
    float* __restrict__ C)
{
    const int wv   = threadIdx.x >> 6;
    const int lane = threadIdx.x & 63;
    const int row  = lane & 15;
    const int quad = lane >> 4;
    const int m0 = blockIdx.x * 256 + wv * 64;
    const int n0 = blockIdx.y * 64;

    ffrag acc[4][4];
#pragma unroll
    for (int mt = 0; mt < 4; ++mt)
#pragma unroll
        for (int n = 0; n < 4; ++n)
#pragma unroll
            for (int r = 0; r < 4; ++r) acc[mt][n][r] = 0.0f;

#pragma unroll 1
    for (int k0 = 0; k0 < 512; k0 += 32) {
        bfrag ahi[4], alo[4];
#pragma unroll
        for (int mt = 0; mt < 4; ++mt) {
            const float* ap = A + (size_t)(m0 + mt * 16 + row) * 512 + k0 + quad * 8;
            float4 aA = *(const float4*)ap;
            float4 aB = *(const float4*)(ap + 4);
            float av[8] = {aA.x, aA.y, aA.z, aA.w, aB.x, aB.y, aB.z, aB.w};
            cvt_hilo(av, ahi[mt], alo[mt]);
        }
#pragma unroll
        for (int n = 0; n < 4; ++n) {
            const float* wp = W + (size_t)(n0 + n * 16 + row) * 512 + k0 + quad * 8;
            float4 wA = *(const float4*)wp;
            float4 wB = *(const float4*)(wp + 4);
            float wvv[8] = {wA.x, wA.y, wA.z, wA.w, wB.x, wB.y, wB.z, wB.w};
            bfrag whi, wlo;
            cvt_hilo(wvv, whi, wlo);
#pragma unroll
            for (int mt = 0; mt < 4; ++mt) {
                acc[mt][n] = __builtin_amdgcn_mfma_f32_16x16x32_bf16(ahi[mt], whi, acc[mt][n], 0, 0, 0);
                acc[mt][n] = __builtin_amdgcn_mfma_f32_16x16x32_bf16(alo[mt], whi, acc[mt][n], 0, 0, 0);
                acc[mt][n] = __builtin_amdgcn_mfma_f32_16x16x32_bf16(ahi[mt], wlo, acc[mt][n], 0, 0, 0);
            }
        }
    }
#pragma unroll
    for (int mt = 0; mt < 4; ++mt)
#pragma unroll
        for (int n = 0; n < 4; ++n)
#pragma unroll
            for (int r = 0; r < 4; ++r)
                C[(size_t)(m0 + mt * 16 + quad * 4 + r) * 512 + n0 + n * 16 + row]
                    = acc[mt][n][r];
}

// ---------------------------------------------------------------------------
// 3-gate MFMA GEMM (R26: 4 M-tiles/wave): fp32 out + biases.
// ---------------------------------------------------------------------------
template<int GATHER>
__global__ __launch_bounds__(256, 2) void mfma_g3_kernel(
    const float* __restrict__ A, const int* __restrict__ gidx,
    int lda, int K,
    const float* __restrict__ W, int ldw,
    const float* __restrict__ bias1, const float* __restrict__ bias2,
    float* __restrict__ out)
{
    const int wv   = threadIdx.x >> 6;
    const int lane = threadIdx.x & 63;
    const int row  = lane & 15;
    const int quad = lane >> 4;
    const int m0   = blockIdx.x * 256 + wv * 64;
    const int gate = blockIdx.y >> 3;
    const int gbase = (gate == 0) ? 0 : (gate == 1 ? 1024 : 1536);
    const int j0   = (blockIdx.y & 7) * 64;

    int arow[4];
#pragma unroll
    for (int mt = 0; mt < 4; ++mt)
        arow[mt] = GATHER ? gidx[m0 + mt * 16 + row] : (m0 + mt * 16 + row);

    ffrag acc[4][4];
#pragma unroll
    for (int mt = 0; mt < 4; ++mt)
#pragma unroll
        for (int n = 0; n < 4; ++n)
#pragma unroll
            for (int r = 0; r < 4; ++r) acc[mt][n][r] = 0.0f;

#pragma unroll 1
    for (int k0 = 0; k0 < K; k0 += 32) {
        const bool tail = (k0 + 32 > K);
        bfrag ahi[4], alo[4];
#pragma unroll
        for (int mt = 0; mt < 4; ++mt) {
            float av[8];
            if (!tail) {
                const float* ap = A + (size_t)arow[mt] * lda + k0 + quad * 8;
                float4 aA = *(const float4*)ap;
                float4 aB = *(const float4*)(ap + 4);
                av[0]=aA.x; av[1]=aA.y; av[2]=aA.z; av[3]=aA.w;
                av[4]=aB.x; av[5]=aB.y; av[6]=aB.z; av[7]=aB.w;
            } else {
#pragma unroll
                for (int z = 0; z < 8; ++z) {
                    int kk = k0 + quad * 8 + z;
                    av[z] = (kk < K) ? A[(size_t)arow[mt] * lda + kk] : 0.0f;
                }
            }
            cvt_hilo(av, ahi[mt], alo[mt]);
        }
#pragma unroll
        for (int n = 0; n < 4; ++n) {
            const int wrow = gbase + j0 + n * 16 + row;
            float wvv[8];
            if (!tail) {
                const float* wp = W + (size_t)wrow * ldw + k0 + quad * 8;
                float4 wA = *(const float4*)wp;
                float4 wB = *(const float4*)(wp + 4);
                wvv[0]=wA.x; wvv[1]=wA.y; wvv[2]=wA.z; wvv[3]=wA.w;
                wvv[4]=wB.x; wvv[5]=wB.y; wvv[6]=wB.z; wvv[7]=wB.w;
            } else {
#pragma unroll
                for (int z = 0; z < 8; ++z) {
                    int kk = k0 + quad * 8 + z;
                    wvv[z] = (kk < K) ? W[(size_t)wrow * ldw + kk] : 0.0f;
                }
            }
            bfrag whi, wlo;
            cvt_hilo(wvv, whi, wlo);
#pragma unroll
            for (int mt = 0; mt < 4; ++mt) {
                acc[mt][n] = __builtin_amdgcn_mfma_f32_16x16x32_bf16(ahi[mt], whi, acc[mt][n], 0, 0, 0);
                acc[mt][n] = __builtin_amdgcn_mfma_f32_16x16x32_bf16(alo[mt], whi, acc[mt][n], 0, 0, 0);
                acc[mt][n] = __builtin_amdgcn_mfma_f32_16x16x32_bf16(ahi[mt], wlo, acc[mt][n], 0, 0, 0);
            }
        }
    }
#pragma unroll
    for (int n = 0; n < 4; ++n) {
        const int j = j0 + n * 16 + row;
        const float bb = bias1[gbase + j] + bias2[gbase + j];
#pragma unroll
        for (int mt = 0; mt < 4; ++mt)
#pragma unroll
            for (int r = 0; r < 4; ++r) {
                const int m = m0 + mt * 16 + quad * 4 + r;
                out[((size_t)m * 3 + gate) * 512 + j] = acc[mt][n][r] + bb;
            }
    }
}

// ---------------------------------------------------------------------------
// G3 GEMM (R26: 4 M-tiles/wave): t-major pack (R25 layout, validated).
// ---------------------------------------------------------------------------
__global__ __launch_bounds__(256, 2) void g3pack_kernel(
    const float* __restrict__ A,            // Rh: 4096 x 512
    const float* __restrict__ W,            // Wih_m, ldw 1024
    unsigned short* __restrict__ G3s,
    int mbase)                              // 0 or 4096
{
    const int wv   = threadIdx.x >> 6;
    const int lane = threadIdx.x & 63;
    const int row  = lane & 15;
    const int quad = lane >> 4;
    const int m0   = blockIdx.x * 256 + wv * 64;
    const int gate = blockIdx.y >> 3;
    const int gbase = (gate == 0) ? 0 : (gate == 1 ? 1024 : 1536);
    const int j0   = (blockIdx.y & 7) * 64;

    ffrag acc[4][4];
#pragma unroll
    for (int mt = 0; mt < 4; ++mt)
#pragma unroll
        for (int n = 0; n < 4; ++n)
#pragma unroll
            for (int r = 0; r < 4; ++r) acc[mt][n][r] = 0.0f;

#pragma unroll 1
    for (int k0 = 0; k0 < 512; k0 += 32) {
        bfrag ahi[4], alo[4];
#pragma unroll
        for (int mt = 0; mt < 4; ++mt) {
            const float* ap = A + (size_t)(m0 + mt * 16 + row) * 512 + k0 + quad * 8;
            float4 aA = *(const float4*)ap;
            float4 aB = *(const float4*)(ap + 4);
            float av[8] = {aA.x, aA.y, aA.z, aA.w, aB.x, aB.y, aB.z, aB.w};
            cvt_hilo(av, ahi[mt], alo[mt]);
        }
#pragma unroll
        for (int n = 0; n < 4; ++n) {
            const int wrow = gbase + j0 + n * 16 + row;
            const float* wp = W + (size_t)wrow * 1024 + k0 + quad * 8;
            float4 wA = *(const float4*)wp;
            float4 wB = *(const float4*)(wp + 4);
            float wvv[8] = {wA.x, wA.y, wA.z, wA.w, wB.x, wB.y, wB.z, wB.w};
            bfrag whi, wlo;
            cvt_hilo(wvv, whi, wlo);
#pragma unroll
            for (int mt = 0; mt < 4; ++mt) {
                acc[mt][n] = __builtin_amdgcn_mfma_f32_16x16x32_bf16(ahi[mt], whi, acc[mt][n], 0, 0, 0);
                acc[mt][n] = __builtin_amdgcn_mfma_f32_16x16x32_bf16(alo[mt], whi, acc[mt][n], 0, 0, 0);
                acc[mt][n] = __builtin_amdgcn_mfma_f32_16x16x32_bf16(ahi[mt], wlo, acc[mt][n], 0, 0, 0);
            }
        }
    }
#pragma unroll
    for (int n = 0; n < 4; ++n) {
        const int j = j0 + n * 16 + row;
#pragma unroll
        for (int mt = 0; mt < 4; ++mt)
#pragma unroll
            for (int r = 0; r < 4; ++r) {
                const int mg = mbase + m0 + mt * 16 + quad * 4 + r;
                const int t = mg >> 7, b = mg & 127;
                size_t idx = (size_t)b * G3_BLK_S
                           + ((size_t)(gate * 512 + j)) * 64 + t;
                G3s[idx] = (unsigned short)f2bf(acc[mt][n][r]);
            }
    }
}

// ---------------------------------------------------------------------------
// Encoder gate math (validated R15).
// ---------------------------------------------------------------------------
__global__ __launch_bounds__(256) void enc_gates_kernel(
    const float* __restrict__ P, float* __restrict__ h)
{
    const int i = blockIdx.x * 256 + threadIdx.x;
    const int m = i >> 7;
    const int j4 = (i & 127) * 4;
    const float* p = P + (size_t)m * 1536 + j4;
    float4 gi = *(const float4*)p;
    float4 gg = *(const float4*)(p + 512);
    float4 go = *(const float4*)(p + 1024);
    float4 r;
    r.x = fast_sigmoid(go.x) * fast_tanh(fast_sigmoid(gi.x) * fast_tanh(gg.x));
    r.y = fast_sigmoid(go.y) * fast_tanh(fast_sigmoid(gi.y) * fast_tanh(gg.y));
    r.z = fast_sigmoid(go.z) * fast_tanh(fast_sigmoid(gi.z) * fast_tanh(gg.z));
    r.w = fast_sigmoid(go.w) * fast_tanh(fast_sigmoid(gi.w) * fast_tanh(gg.w));
    *(float4*)&h[(size_t)m * 512 + j4] = r;
}

// ---------------------------------------------------------------------------
// Wm pack (validated R19): [kc][nt][lane] tile-interleaved.
// ---------------------------------------------------------------------------
__global__ __launch_bounds__(256) void pack_wm_kernel(
    const float* __restrict__ Wm, unsigned* __restrict__ WmB)
{
    int i = blockIdx.x * 256 + threadIdx.x;           // 0 .. 131071
    int u = i & 3, lane = (i >> 2) & 63;
    int nt = (i >> 8) & 31, kc = i >> 13;
    int row = nt * 16 + (lane & 15);
    int k = kc * 32 + ((lane >> 4) << 3) + u * 2;
    unsigned lo = f2bf(Wm[(size_t)row * 512 + k]);
    unsigned hi = f2bf(Wm[(size_t)row * 512 + k + 1]);
    WmB[i] = lo | (hi << 16);
}

// ---------------------------------------------------------------------------
// Phase B (R25 verbatim): GEMV1 K-split + MFMA G3-sum (t-major).
// ---------------------------------------------------------------------------
__global__ __launch_bounds__(1024) void phaseB_kernel(
    const float* __restrict__ pre_s, const float* __restrict__ pre_t,
    const float* __restrict__ pre_m_h,
    const unsigned* __restrict__ WmB, const unsigned short* __restrict__ G3s,
    const float* __restrict__ w_e,
    const float* __restrict__ fc_w,  const float* __restrict__ fc_b,
    float* __restrict__ out)
{
    extern __shared__ __align__(16) float psL[];      // 64*512 fp32 = 128KB
    __shared__ __align__(16) float hm[512];
    __shared__ __align__(16) float base[512];
    __shared__ __align__(16) float wesh[512];
    __shared__ __align__(16) float sc[64];
    __shared__ __align__(16) float red[2 * 512];
    __shared__ __align__(16) float gates3[1536];
    __shared__ __align__(16) unsigned short hmh[512];
    __shared__ __align__(16) unsigned short hml[512];
    __shared__ __align__(16) unsigned short sch[64];
    __shared__ __align__(16) unsigned short scl[64];

    const int b    = blockIdx.x;
    const int tid  = threadIdx.x;
    const int wv   = tid >> 6;
    const int lane = tid & 63;
    const int col  = lane & 15;
    const int quad = lane >> 4;

    if (tid < 512) {
        wesh[tid] = w_e[tid];
        hm[tid] = 0.0f; hmh[tid] = 0; hml[tid] = 0;
    }
    for (int i = tid; i < 32768; i += 1024) {
        int t = i >> 9, h = i & 511;
        psL[i] = ntload(&pre_s[((size_t)t * 128 + b) * 512 + h]);
    }
    __syncthreads();

    for (int k = 0; k < 64; ++k) {
        // ---- GEMV1 (K-split): partials for base = Wm . hm
        {
            const int kh2 = wv >> 3;
            const int tp  = (wv & 7) * 4;
            ffrag a0 = {0.0f,0.0f,0.0f,0.0f}, a1 = {0.0f,0.0f,0.0f,0.0f};
            ffrag a2 = {0.0f,0.0f,0.0f,0.0f}, a3 = {0.0f,0.0f,0.0f,0.0f};
            const uint4* wp = (const uint4*)WmB
                            + ((size_t)(kh2 * 8) * 32 + tp) * 64 + lane;
            const unsigned short* ab = ((lane & 8) == 0) ? hmh : hml;
#pragma unroll 1
            for (int kc = 0; kc < 8; ++kc) {
                bfrag a  = *(const bfrag*)&ab[(kh2 * 8 + kc) * 32 + quad * 8];
                bfrag w0 = *(const bfrag*)(wp);
                bfrag w1 = *(const bfrag*)(wp + 64);
                bfrag w2 = *(const bfrag*)(wp + 128);
                bfrag w3 = *(const bfrag*)(wp + 192);
                a0 = __builtin_amdgcn_mfma_f32_16x16x32_bf16(a, w0, a0, 0, 0, 0);
                a1 = __builtin_amdgcn_mfma_f32_16x16x32_bf16(a, w1, a1, 0, 0, 0);
                a2 = __builtin_amdgcn_mfma_f32_16x16x32_bf16(a, w2, a2, 0, 0, 0);
                a3 = __builtin_amdgcn_mfma_f32_16x16x32_bf16(a, w3, a3, 0, 0, 0);
                wp += 2048;
            }
            float s0 = a0[0] + __shfl_xor(a0[0], 32);
            float s1 = a1[0] + __shfl_xor(a1[0], 32);
            float s2 = a2[0] + __shfl_xor(a2[0], 32);
            float s3 = a3[0] + __shfl_xor(a3[0], 32);
            if (lane < 16) {
                float* rr = &red[kh2 * 512];
                rr[(tp + 0) * 16 + lane] = s0;
                rr[(tp + 1) * 16 + lane] = s1;
                rr[(tp + 2) * 16 + lane] = s2;
                rr[(tp + 3) * 16 + lane] = s3;
            }
        }
        __syncthreads();
        if (tid < 512)
            base[tid] = red[tid] + red[512 + tid]
                      + ntload(&pre_t[((size_t)k * 128 + b) * 512 + tid]);
        __syncthreads();

        // ---- attention scores: e[t] = w_e . tanh(psL[t] + base)  (all LDS)
#pragma unroll
        for (int tt = 0; tt < 4; ++tt) {
            int t = wv * 4 + tt;
            const float* ps = &psL[t * 512];
            float p = 0.0f;
#pragma unroll
            for (int u = 0; u < 8; ++u) {
                int h = lane + 64 * u;
                p += wesh[h] * fast_tanh(ps[h] + base[h]);
            }
#pragma unroll
            for (int off = 32; off; off >>= 1) p += __shfl_xor(p, off);
            if (lane == 0) sc[t] = p;
        }
        __syncthreads();

        // ---- softmax (+ bf16 hi/lo pack of alpha)
        if (wv == 0) {
            float s = sc[lane], mx = s;
#pragma unroll
            for (int off = 32; off; off >>= 1) mx = fmaxf(mx, __shfl_xor(mx, off));
            float e = __expf(s - mx), sum = e;
#pragma unroll
            for (int off = 32; off; off >>= 1) sum += __shfl_xor(sum, off);
            float a = e / sum;
            unsigned hb = f2bf(a);
            sch[lane] = (unsigned short)hb;
            scl[lane] = (unsigned short)f2bf(a - blo(hb));
        }
        __syncthreads();

        // ---- gates = sum_t alpha_t * G3T[b][:,t]  via MFMA (K=64)
        {
            const unsigned short* ab = ((lane & 8) == 0) ? sch : scl;
            bfrag aA = *(const bfrag*)&ab[quad * 8];
            bfrag aB = *(const bfrag*)&ab[32 + quad * 8];
            const unsigned short* gp = G3s + (size_t)b * G3_BLK_S
                                     + ((size_t)(wv * 96) + col) * 64 + quad * 8;
            ffrag g[6];
#pragma unroll
            for (int t6 = 0; t6 < 6; ++t6) {
                g[t6][0] = 0.0f; g[t6][1] = 0.0f; g[t6][2] = 0.0f; g[t6][3] = 0.0f;
            }
#pragma unroll
            for (int t6 = 0; t6 < 6; ++t6) {
                bfrag w0 = *(const bfrag*)(gp + t6 * 1024);
                g[t6] = __builtin_amdgcn_mfma_f32_16x16x32_bf16(aA, w0, g[t6], 0, 0, 0);
            }
#pragma unroll
            for (int t6 = 0; t6 < 6; ++t6) {
                bfrag w1 = *(const bfrag*)(gp + t6 * 1024 + 32);
                g[t6] = __builtin_amdgcn_mfma_f32_16x16x32_bf16(aB, w1, g[t6], 0, 0, 0);
            }
#pragma unroll
            for (int t6 = 0; t6 < 6; ++t6) {
                float s = g[t6][0] + __shfl_xor(g[t6][0], 32);
                if (lane < 16) gates3[(wv * 6 + t6) * 16 + lane] = s;
            }
        }
        __syncthreads();

        // ---- gate math -> hm (+ hi/lo pack for next step's GEMV1)
        if (tid < 512) {
            const size_t m = (size_t)k * 128 + b;
            float gi = gates3[tid]        + ntload(&pre_m_h[(m * 3 + 0) * 512 + tid]);
            float gg = gates3[512 + tid]  + ntload(&pre_m_h[(m * 3 + 1) * 512 + tid]);
            float go = gates3[1024 + tid] + ntload(&pre_m_h[(m * 3 + 2) * 512 + tid]);
            float cc = fast_sigmoid(gi) * fast_tanh(gg);
            float hv = fast_sigmoid(go) * fast_tanh(cc);
            hm[tid] = hv;
            unsigned hb = f2bf(hv);
            hmh[tid] = (unsigned short)hb;
            hml[tid] = (unsigned short)f2bf(hv - blo(hb));
        }
        __syncthreads();
    }

    if (wv < 3) {
        float p = 0.0f;
#pragma unroll
        for (int u = 0; u < 8; ++u) {
            int h = lane + 64 * u;
            p += hm[h] * fc_w[wv * 512 + h];
        }
#pragma unroll
        for (int off = 32; off; off >>= 1) p += __shfl_xor(p, off);
        if (lane == 0) out[b * 3 + wv] = p + fc_b[wv];
    }
}

extern "C" void kernel_launch(void* const* d_in, const int* in_sizes, int n_in,
                              void* d_out, int out_size, void* d_ws, size_t ws_size,
                              hipStream_t stream)
{
    (void)in_sizes; (void)n_in; (void)out_size;
    const int*   premise    = (const int*)d_in[0];
    const int*   hypothesis = (const int*)d_in[2];
    const float* embed  = (const float*)d_in[4];
    const float* w_e    = (const float*)d_in[5];
    const float* Ws     = (const float*)d_in[6];
    const float* Wt     = (const float*)d_in[7];
    const float* Wm     = (const float*)d_in[8];
    const float* Wih_p  = (const float*)d_in[9];
    const float* bih_p  = (const float*)d_in[10];
    const float* bhh_p  = (const float*)d_in[11];
    const float* Wih_h  = (const float*)d_in[12];
    const float* bih_h  = (const float*)d_in[13];
    const float* bhh_h  = (const float*)d_in[14];
    const float* Wih_m  = (const float*)d_in[15];
    const float* bih_m  = (const float*)d_in[16];
    const float* bhh_m  = (const float*)d_in[17];
    const float* fc_w   = (const float*)d_in[18];
    const float* fc_b   = (const float*)d_in[19];

    // Workspace layout (floats), total 29,425,664 <= guard 29,556,736:
    //   Rh      @ 0         : 2,097,152  (half-scratch; WmB aliases)
    //   pre_s   @ 2,097,152 : 4,194,304
    //   pre_t   @ 6,291,456 : 4,194,304
    //   pre_m_h @10,485,760 :12,582,912  (halves also = encoder preact P)
    //   G3      @23,068,672 : 6,356,992  (bf16 t-major, 194KB/block padded)
    float* ws      = (float*)d_ws;
    float* Rh      = ws;
    float* pre_s   = ws + 2097152;
    float* pre_t   = ws + 6291456;
    float* pre_m_h = ws + 10485760;
    unsigned short* G3s = (unsigned short*)(ws + 23068672);
    unsigned* WmB  = (unsigned*)Rh;           // aliases Rh after last reader
    float* outp    = (float*)d_out;
    if (ws_size < (size_t)29556736 * 4) return;

    dim3 blk(256);

    // ---- Phase A: premise halves -> h_s(half) -> pre_s(half), G3(half)
    for (int h = 0; h < 2; ++h) {
        float* P = pre_m_h + (size_t)h * 6291456;
        mfma_g3_kernel<1><<<dim3(16, 24), blk, 0, stream>>>(
            embed, premise + h * 4096, 300, 300, Wih_p, 300, bih_p, bhh_p, P);
        enc_gates_kernel<<<2048, blk, 0, stream>>>(P, Rh);
        mfma_nt_kernel<<<dim3(16, 8), blk, 0, stream>>>(
            Rh, Ws, pre_s + (size_t)h * 2097152);
        g3pack_kernel<<<dim3(16, 24), blk, 0, stream>>>(
            Rh, Wih_m, G3s, h * 4096);
    }
    // ---- Phase A: hypothesis halves -> h_t(half) -> pre_t(half), pre_m_h(half)
    for (int h = 0; h < 2; ++h) {
        float* P = pre_m_h + (size_t)h * 6291456;
        mfma_g3_kernel<1><<<dim3(16, 24), blk, 0, stream>>>(
            embed, hypothesis + h * 4096, 300, 300, Wih_h, 300, bih_h, bhh_h, P);
        enc_gates_kernel<<<2048, blk, 0, stream>>>(P, Rh);
        mfma_nt_kernel<<<dim3(16, 8), blk, 0, stream>>>(
            Rh, Wt, pre_t + (size_t)h * 2097152);
        mfma_g3_kernel<0><<<dim3(16, 24), blk, 0, stream>>>(
            Rh, nullptr, 512, 512, Wih_m + 512, 1024, bih_m, bhh_m,
            pre_m_h + (size_t)h * 6291456);
    }

    // ---- Wm pack (after Rh's last reader; output aliases Rh)
    pack_wm_kernel<<<512, blk, 0, stream>>>(Wm, WmB);

    // ---- Phase B (128KB dynamic LDS for pre_s cache)
    static int attr_done = 0;
    if (!attr_done) {
        hipFuncSetAttribute((const void*)phaseB_kernel,
                            hipFuncAttributeMaxDynamicSharedMemorySize, 131072);
        attr_done = 1;
    }
    phaseB_kernel<<<dim3(128), dim3(1024), 131072, stream>>>(
        pre_s, pre_t, pre_m_h, WmB, G3s, w_e, fc_w, fc_b, outp);
}

// Round 12
// 1432.223 us; speedup vs baseline: 1.2959x; 1.0859x over previous
//
#include <hip/hip_runtime.h>

// MatchLSTM forward (Round 27): pre-packed A-fragments for phase A.
//   R26 post-mortem: density fix helped (940->800us) but in-loop A-side
//   cvt_hilo (4 A-cvts ~100 VALU per k0) remains, and every y-block
//   re-converts the SAME A rows (8-24x redundant). R27: enc_gates writes h
//   directly as bf16 hi/lo MFMA A-frags (RhB, WmB-style [kc][mt][lane]
//   {hi,lo} uint4 pairs). Consumer GEMMs (nt, g3pack, g3<0>->g3_packedA)
//   load ahi/alo as 2x uint4 -> zero in-loop A-cvt. Same values, same MFMA
//   order -> BIT-IDENTICAL (absmax must stay 0.0009765625 exactly).
//   Gather-GEMM (embed, K=300) keeps fp32 path. RhB = exactly the old Rh
//   slot (4.19M ushorts = 2.097M floats). phaseB: R25 verbatim.

#define DEV static __device__ __forceinline__

DEV float fast_sigmoid(float x) { return 1.0f / (1.0f + __expf(-x)); }
DEV float fast_tanh(float x)    { return 1.0f - 2.0f / (__expf(2.0f * x) + 1.0f); }

DEV unsigned f2bf(float x) {
    unsigned v = __float_as_uint(x);
    return (v + 0x7FFFu + ((v >> 16) & 1u)) >> 16;
}
DEV float blo(unsigned u) { return __uint_as_float(u << 16); }

DEV float ntload(const float* p) { return __builtin_nontemporal_load(p); }

typedef __attribute__((ext_vector_type(8))) short bfrag;   // 8 bf16
typedef __attribute__((ext_vector_type(4))) float ffrag;   // 4 fp32 acc

// G3 block region (ushorts): 1536*64 data + 1024 pad = 99328 = 194KB
#define G3_BLK_S 99328

DEV void cvt_hilo(const float* v, bfrag& hi, bfrag& lo)
{
#pragma unroll
    for (int z = 0; z < 8; ++z) {
        unsigned h = f2bf(v[z]);
        hi[z] = (short)h;
        lo[z] = (short)f2bf(v[z] - __uint_as_float(h << 16));
    }
}

// ---------------------------------------------------------------------------
// MFMA GEMM (R27): C[M][512] = A_packed . W[512][512]^T, 4 M-tiles/wave.
// A from RhB (bf16 hi/lo frags): base u4 = ((kc*256 + mtile)*64 + lane)*2.
// ---------------------------------------------------------------------------
__global__ __launch_bounds__(256, 2) void mfma_nt_kernel(
    const uint4* __restrict__ AB, const float* __restrict__ W,
    float* __restrict__ C)
{
    const int wv   = threadIdx.x >> 6;
    const int lane = threadIdx.x & 63;
    const int row  = lane & 15;
    const int quad = lane >> 4;
    const int m0 = blockIdx.x * 256 + wv * 64;
    const int n0 = blockIdx.y * 64;
    const int mt0 = m0 >> 4;                       // first of 4 m-tiles

    ffrag acc[4][4];
#pragma unroll
    for (int mt = 0; mt < 4; ++mt)
#pragma unroll
        for (int n = 0; n < 4; ++n)
#pragma unroll
            for (int r = 0; r < 4; ++r) acc[mt][n][r] = 0.0f;

#pragma unroll 1
    for (int k0 = 0; k0 < 512; k0 += 32) {
        const int kc = k0 >> 5;
        bfrag ahi[4], alo[4];
#pragma unroll
        for (int mt = 0; mt < 4; ++mt) {
            const uint4* ap = AB + ((size_t)(kc * 256 + mt0 + mt) * 64 + lane) * 2;
            ahi[mt] = *(const bfrag*)(ap);
            alo[mt] = *(const bfrag*)(ap + 1);
        }
#pragma unroll
        for (int n = 0; n < 4; ++n) {
            const float* wp = W + (size_t)(n0 + n * 16 + row) * 512 + k0 + quad * 8;
            float4 wA = *(const float4*)wp;
            float4 wB = *(const float4*)(wp + 4);
            float wvv[8] = {wA.x, wA.y, wA.z, wA.w, wB.x, wB.y, wB.z, wB.w};
            bfrag whi, wlo;
            cvt_hilo(wvv, whi, wlo);
#pragma unroll
            for (int mt = 0; mt < 4; ++mt) {
                acc[mt][n] = __builtin_amdgcn_mfma_f32_16x16x32_bf16(ahi[mt], whi, acc[mt][n], 0, 0, 0);
                acc[mt][n] = __builtin_amdgcn_mfma_f32_16x16x32_bf16(alo[mt], whi, acc[mt][n], 0, 0, 0);
                acc[mt][n] = __builtin_amdgcn_mfma_f32_16x16x32_bf16(ahi[mt], wlo, acc[mt][n], 0, 0, 0);
            }
        }
    }
#pragma unroll
    for (int mt = 0; mt < 4; ++mt)
#pragma unroll
        for (int n = 0; n < 4; ++n)
#pragma unroll
            for (int r = 0; r < 4; ++r)
                C[(size_t)(m0 + mt * 16 + quad * 4 + r) * 512 + n0 + n * 16 + row]
                    = acc[mt][n][r];
}

// ---------------------------------------------------------------------------
// Gather 3-gate GEMM (R26 path, fp32 A from embed, K=300): validated.
// ---------------------------------------------------------------------------
__global__ __launch_bounds__(256, 2) void g3_gather_kernel(
    const float* __restrict__ A, const int* __restrict__ gidx,
    int lda, int K,
    const float* __restrict__ W, int ldw,
    const float* __restrict__ bias1, const float* __restrict__ bias2,
    float* __restrict__ out)
{
    const int wv   = threadIdx.x >> 6;
    const int lane = threadIdx.x & 63;
    const int row  = lane & 15;
    const int quad = lane >> 4;
    const int m0   = blockIdx.x * 256 + wv * 64;
    const int gate = blockIdx.y >> 3;
    const int gbase = (gate == 0) ? 0 : (gate == 1 ? 1024 : 1536);
    const int j0   = (blockIdx.y & 7) * 64;

    int arow[4];
#pragma unroll
    for (int mt = 0; mt < 4; ++mt)
        arow[mt] = gidx[m0 + mt * 16 + row];

    ffrag acc[4][4];
#pragma unroll
    for (int mt = 0; mt < 4; ++mt)
#pragma unroll
        for (int n = 0; n < 4; ++n)
#pragma unroll
            for (int r = 0; r < 4; ++r) acc[mt][n][r] = 0.0f;

#pragma unroll 1
    for (int k0 = 0; k0 < K; k0 += 32) {
        const bool tail = (k0 + 32 > K);
        bfrag ahi[4], alo[4];
#pragma unroll
        for (int mt = 0; mt < 4; ++mt) {
            float av[8];
            if (!tail) {
                const float* ap = A + (size_t)arow[mt] * lda + k0 + quad * 8;
                float4 aA = *(const float4*)ap;
                float4 aB = *(const float4*)(ap + 4);
                av[0]=aA.x; av[1]=aA.y; av[2]=aA.z; av[3]=aA.w;
                av[4]=aB.x; av[5]=aB.y; av[6]=aB.z; av[7]=aB.w;
            } else {
#pragma unroll
                for (int z = 0; z < 8; ++z) {
                    int kk = k0 + quad * 8 + z;
                    av[z] = (kk < K) ? A[(size_t)arow[mt] * lda + kk] : 0.0f;
                }
            }
            cvt_hilo(av, ahi[mt], alo[mt]);
        }
#pragma unroll
        for (int n = 0; n < 4; ++n) {
            const int wrow = gbase + j0 + n * 16 + row;
            float wvv[8];
            if (!tail) {
                const float* wp = W + (size_t)wrow * ldw + k0 + quad * 8;
                float4 wA = *(const float4*)wp;
                float4 wB = *(const float4*)(wp + 4);
                wvv[0]=wA.x; wvv[1]=wA.y; wvv[2]=wA.z; wvv[3]=wA.w;
                wvv[4]=wB.x; wvv[5]=wB.y; wvv[6]=wB.z; wvv[7]=wB.w;
            } else {
#pragma unroll
                for (int z = 0; z < 8; ++z) {
                    int kk = k0 + quad * 8 + z;
                    wvv[z] = (kk < K) ? W[(size_t)wrow * ldw + kk] : 0.0f;
                }
            }
            bfrag whi, wlo;
            cvt_hilo(wvv, whi, wlo);
#pragma unroll
            for (int mt = 0; mt < 4; ++mt) {
                acc[mt][n] = __builtin_amdgcn_mfma_f32_16x16x32_bf16(ahi[mt], whi, acc[mt][n], 0, 0, 0);
                acc[mt][n] = __builtin_amdgcn_mfma_f32_16x16x32_bf16(alo[mt], whi, acc[mt][n], 0, 0, 0);
                acc[mt][n] = __builtin_amdgcn_mfma_f32_16x16x32_bf16(ahi[mt], wlo, acc[mt][n], 0, 0, 0);
            }
        }
    }
#pragma unroll
    for (int n = 0; n < 4; ++n) {
        const int j = j0 + n * 16 + row;
        const float bb = bias1[gbase + j] + bias2[gbase + j];
#pragma unroll
        for (int mt = 0; mt < 4; ++mt)
#pragma unroll
            for (int r = 0; r < 4; ++r) {
                const int m = m0 + mt * 16 + quad * 4 + r;
                out[((size_t)m * 3 + gate) * 512 + j] = acc[mt][n][r] + bb;
            }
    }
}

// ---------------------------------------------------------------------------
// 3-gate GEMM, packed A (R27): A from RhB; K=512; fp32 out + biases.
// ---------------------------------------------------------------------------
__global__ __launch_bounds__(256, 2) void g3_packedA_kernel(
    const uint4* __restrict__ AB,
    const float* __restrict__ W, int ldw,
    const float* __restrict__ bias1, const float* __restrict__ bias2,
    float* __restrict__ out)
{
    const int wv   = threadIdx.x >> 6;
    const int lane = threadIdx.x & 63;
    const int row  = lane & 15;
    const int quad = lane >> 4;
    const int m0   = blockIdx.x * 256 + wv * 64;
    const int gate = blockIdx.y >> 3;
    const int gbase = (gate == 0) ? 0 : (gate == 1 ? 1024 : 1536);
    const int j0   = (blockIdx.y & 7) * 64;
    const int mt0  = m0 >> 4;

    ffrag acc[4][4];
#pragma unroll
    for (int mt = 0; mt < 4; ++mt)
#pragma unroll
        for (int n = 0; n < 4; ++n)
#pragma unroll
            for (int r = 0; r < 4; ++r) acc[mt][n][r] = 0.0f;

#pragma unroll 1
    for (int k0 = 0; k0 < 512; k0 += 32) {
        const int kc = k0 >> 5;
        bfrag ahi[4], alo[4];
#pragma unroll
        for (int mt = 0; mt < 4; ++mt) {
            const uint4* ap = AB + ((size_t)(kc * 256 + mt0 + mt) * 64 + lane) * 2;
            ahi[mt] = *(const bfrag*)(ap);
            alo[mt] = *(const bfrag*)(ap + 1);
        }
#pragma unroll
        for (int n = 0; n < 4; ++n) {
            const int wrow = gbase + j0 + n * 16 + row;
            const float* wp = W + (size_t)wrow * ldw + k0 + quad * 8;
            float4 wA = *(const float4*)wp;
            float4 wB = *(const float4*)(wp + 4);
            float wvv[8] = {wA.x, wA.y, wA.z, wA.w, wB.x, wB.y, wB.z, wB.w};
            bfrag whi, wlo;
            cvt_hilo(wvv, whi, wlo);
#pragma unroll
            for (int mt = 0; mt < 4; ++mt) {
                acc[mt][n] = __builtin_amdgcn_mfma_f32_16x16x32_bf16(ahi[mt], whi, acc[mt][n], 0, 0, 0);
                acc[mt][n] = __builtin_amdgcn_mfma_f32_16x16x32_bf16(alo[mt], whi, acc[mt][n], 0, 0, 0);
                acc[mt][n] = __builtin_amdgcn_mfma_f32_16x16x32_bf16(ahi[mt], wlo, acc[mt][n], 0, 0, 0);
            }
        }
    }
#pragma unroll
    for (int n = 0; n < 4; ++n) {
        const int j = j0 + n * 16 + row;
        const float bb = bias1[gbase + j] + bias2[gbase + j];
#pragma unroll
        for (int mt = 0; mt < 4; ++mt)
#pragma unroll
            for (int r = 0; r < 4; ++r) {
                const int m = m0 + mt * 16 + quad * 4 + r;
                out[((size_t)m * 3 + gate) * 512 + j] = acc[mt][n][r] + bb;
            }
    }
}

// ---------------------------------------------------------------------------
// G3 GEMM (R27): packed A; t-major G3 output (R25 layout, validated).
// ---------------------------------------------------------------------------
__global__ __launch_bounds__(256, 2) void g3pack_kernel(
    const uint4* __restrict__ AB,
    const float* __restrict__ W,            // Wih_m, ldw 1024
    unsigned short* __restrict__ G3s,
    int mbase)                              // 0 or 4096
{
    const int wv   = threadIdx.x >> 6;
    const int lane = threadIdx.x & 63;
    const int row  = lane & 15;
    const int quad = lane >> 4;
    const int m0   = blockIdx.x * 256 + wv * 64;
    const int gate = blockIdx.y >> 3;
    const int gbase = (gate == 0) ? 0 : (gate == 1 ? 1024 : 1536);
    const int j0   = (blockIdx.y & 7) * 64;
    const int mt0  = m0 >> 4;

    ffrag acc[4][4];
#pragma unroll
    for (int mt = 0; mt < 4; ++mt)
#pragma unroll
        for (int n = 0; n < 4; ++n)
#pragma unroll
            for (int r = 0; r < 4; ++r) acc[mt][n][r] = 0.0f;

#pragma unroll 1
    for (int k0 = 0; k0 < 512; k0 += 32) {
        const int kc = k0 >> 5;
        bfrag ahi[4], alo[4];
#pragma unroll
        for (int mt = 0; mt < 4; ++mt) {
            const uint4* ap = AB + ((size_t)(kc * 256 + mt0 + mt) * 64 + lane) * 2;
            ahi[mt] = *(const bfrag*)(ap);
            alo[mt] = *(const bfrag*)(ap + 1);
        }
#pragma unroll
        for (int n = 0; n < 4; ++n) {
            const int wrow = gbase + j0 + n * 16 + row;
            const float* wp = W + (size_t)wrow * 1024 + k0 + quad * 8;
            float4 wA = *(const float4*)wp;
            float4 wB = *(const float4*)(wp + 4);
            float wvv[8] = {wA.x, wA.y, wA.z, wA.w, wB.x, wB.y, wB.z, wB.w};
            bfrag whi, wlo;
            cvt_hilo(wvv, whi, wlo);
#pragma unroll
            for (int mt = 0; mt < 4; ++mt) {
                acc[mt][n] = __builtin_amdgcn_mfma_f32_16x16x32_bf16(ahi[mt], whi, acc[mt][n], 0, 0, 0);
                acc[mt][n] = __builtin_amdgcn_mfma_f32_16x16x32_bf16(alo[mt], whi, acc[mt][n], 0, 0, 0);
                acc[mt][n] = __builtin_amdgcn_mfma_f32_16x16x32_bf16(ahi[mt], wlo, acc[mt][n], 0, 0, 0);
            }
        }
    }
#pragma unroll
    for (int n = 0; n < 4; ++n) {
        const int j = j0 + n * 16 + row;
#pragma unroll
        for (int mt = 0; mt < 4; ++mt)
#pragma unroll
            for (int r = 0; r < 4; ++r) {
                const int mg = mbase + m0 + mt * 16 + quad * 4 + r;
                const int t = mg >> 7, b = mg & 127;
                size_t idx = (size_t)b * G3_BLK_S
                           + ((size_t)(gate * 512 + j)) * 64 + t;
                G3s[idx] = (unsigned short)f2bf(acc[mt][n][r]);
            }
    }
}

// ---------------------------------------------------------------------------
// Encoder gate math + A-frag pack (R27): writes h as bf16 hi/lo fragments.
//   For element (m, k): mt=m>>4, lane=((k>>3)&3)*16 + (m&15), kc=k>>5,
//   z=k&7. hi ushort at ((kc*256+mt)*64+lane)*16 + z; lo at +8.
// ---------------------------------------------------------------------------
__global__ __launch_bounds__(256) void enc_pack_kernel(
    const float* __restrict__ P, unsigned short* __restrict__ RhB)
{
    const int i = blockIdx.x * 256 + threadIdx.x;     // 0 .. 524287
    const int m = i >> 7;
    const int j4 = (i & 127) * 4;
    const float* p = P + (size_t)m * 1536 + j4;
    float4 gi = *(const float4*)p;
    float4 gg = *(const float4*)(p + 512);
    float4 go = *(const float4*)(p + 1024);
    float r[4];
    r[0] = fast_sigmoid(go.x) * fast_tanh(fast_sigmoid(gi.x) * fast_tanh(gg.x));
    r[1] = fast_sigmoid(go.y) * fast_tanh(fast_sigmoid(gi.y) * fast_tanh(gg.y));
    r[2] = fast_sigmoid(go.z) * fast_tanh(fast_sigmoid(gi.z) * fast_tanh(gg.z));
    r[3] = fast_sigmoid(go.w) * fast_tanh(fast_sigmoid(gi.w) * fast_tanh(gg.w));

    const int mt   = m >> 4;
    const int lane = (((j4 >> 3) & 3) << 4) + (m & 15);
    const int kc   = j4 >> 5;
    const int z0   = j4 & 7;                           // 0 or 4
    unsigned short* hi = RhB + ((size_t)(kc * 256 + mt) * 64 + lane) * 16 + z0;
    unsigned short* lo = hi + 8;
#pragma unroll
    for (int t = 0; t < 4; ++t) {
        unsigned hb = f2bf(r[t]);
        hi[t] = (unsigned short)hb;
        lo[t] = (unsigned short)f2bf(r[t] - blo(hb));
    }
}

// ---------------------------------------------------------------------------
// Wm pack (validated R19): [kc][nt][lane] tile-interleaved.
// ---------------------------------------------------------------------------
__global__ __launch_bounds__(256) void pack_wm_kernel(
    const float* __restrict__ Wm, unsigned* __restrict__ WmB)
{
    int i = blockIdx.x * 256 + threadIdx.x;           // 0 .. 131071
    int u = i & 3, lane = (i >> 2) & 63;
    int nt = (i >> 8) & 31, kc = i >> 13;
    int row = nt * 16 + (lane & 15);
    int k = kc * 32 + ((lane >> 4) << 3) + u * 2;
    unsigned lo = f2bf(Wm[(size_t)row * 512 + k]);
    unsigned hi = f2bf(Wm[(size_t)row * 512 + k + 1]);
    WmB[i] = lo | (hi << 16);
}

// ---------------------------------------------------------------------------
// Phase B (R25 verbatim): GEMV1 K-split + MFMA G3-sum (t-major).
// ---------------------------------------------------------------------------
__global__ __launch_bounds__(1024) void phaseB_kernel(
    const float* __restrict__ pre_s, const float* __restrict__ pre_t,
    const float* __restrict__ pre_m_h,
    const unsigned* __restrict__ WmB, const unsigned short* __restrict__ G3s,
    const float* __restrict__ w_e,
    const float* __restrict__ fc_w,  const float* __restrict__ fc_b,
    float* __restrict__ out)
{
    extern __shared__ __align__(16) float psL[];      // 64*512 fp32 = 128KB
    __shared__ __align__(16) float hm[512];
    __shared__ __align__(16) float base[512];
    __shared__ __align__(16) float wesh[512];
    __shared__ __align__(16) float sc[64];
    __shared__ __align__(16) float red[2 * 512];
    __shared__ __align__(16) float gates3[1536];
    __shared__ __align__(16) unsigned short hmh[512];
    __shared__ __align__(16) unsigned short hml[512];
    __shared__ __align__(16) unsigned short sch[64];
    __shared__ __align__(16) unsigned short scl[64];

    const int b    = blockIdx.x;
    const int tid  = threadIdx.x;
    const int wv   = tid >> 6;
    const int lane = tid & 63;
    const int col  = lane & 15;
    const int quad = lane >> 4;

    if (tid < 512) {
        wesh[tid] = w_e[tid];
        hm[tid] = 0.0f; hmh[tid] = 0; hml[tid] = 0;
    }
    for (int i = tid; i < 32768; i += 1024) {
        int t = i >> 9, h = i & 511;
        psL[i] = ntload(&pre_s[((size_t)t * 128 + b) * 512 + h]);
    }
    __syncthreads();

    for (int k = 0; k < 64; ++k) {
        // ---- GEMV1 (K-split): partials for base = Wm . hm
        {
            const int kh2 = wv >> 3;
            const int tp  = (wv & 7) * 4;
            ffrag a0 = {0.0f,0.0f,0.0f,0.0f}, a1 = {0.0f,0.0f,0.0f,0.0f};
            ffrag a2 = {0.0f,0.0f,0.0f,0.0f}, a3 = {0.0f,0.0f,0.0f,0.0f};
            const uint4* wp = (const uint4*)WmB
                            + ((size_t)(kh2 * 8) * 32 + tp) * 64 + lane;
            const unsigned short* ab = ((lane & 8) == 0) ? hmh : hml;
#pragma unroll 1
            for (int kc = 0; kc < 8; ++kc) {
                bfrag a  = *(const bfrag*)&ab[(kh2 * 8 + kc) * 32 + quad * 8];
                bfrag w0 = *(const bfrag*)(wp);
                bfrag w1 = *(const bfrag*)(wp + 64);
                bfrag w2 = *(const bfrag*)(wp + 128);
                bfrag w3 = *(const bfrag*)(wp + 192);
                a0 = __builtin_amdgcn_mfma_f32_16x16x32_bf16(a, w0, a0, 0, 0, 0);
                a1 = __builtin_amdgcn_mfma_f32_16x16x32_bf16(a, w1, a1, 0, 0, 0);
                a2 = __builtin_amdgcn_mfma_f32_16x16x32_bf16(a, w2, a2, 0, 0, 0);
                a3 = __builtin_amdgcn_mfma_f32_16x16x32_bf16(a, w3, a3, 0, 0, 0);
                wp += 2048;
            }
            float s0 = a0[0] + __shfl_xor(a0[0], 32);
            float s1 = a1[0] + __shfl_xor(a1[0], 32);
            float s2 = a2[0] + __shfl_xor(a2[0], 32);
            float s3 = a3[0] + __shfl_xor(a3[0], 32);
            if (lane < 16) {
                float* rr = &red[kh2 * 512];
                rr[(tp + 0) * 16 + lane] = s0;
                rr[(tp + 1) * 16 + lane] = s1;
                rr[(tp + 2) * 16 + lane] = s2;
                rr[(tp + 3) * 16 + lane] = s3;
            }
        }
        __syncthreads();
        if (tid < 512)
            base[tid] = red[tid] + red[512 + tid]
                      + ntload(&pre_t[((size_t)k * 128 + b) * 512 + tid]);
        __syncthreads();

        // ---- attention scores: e[t] = w_e . tanh(psL[t] + base)  (all LDS)
#pragma unroll
        for (int tt = 0; tt < 4; ++tt) {
            int t = wv * 4 + tt;
            const float* ps = &psL[t * 512];
            float p = 0.0f;
#pragma unroll
            for (int u = 0; u < 8; ++u) {
                int h = lane + 64 * u;
                p += wesh[h] * fast_tanh(ps[h] + base[h]);
            }
#pragma unroll
            for (int off = 32; off; off >>= 1) p += __shfl_xor(p, off);
            if (lane == 0) sc[t] = p;
        }
        __syncthreads();

        // ---- softmax (+ bf16 hi/lo pack of alpha)
        if (wv == 0) {
            float s = sc[lane], mx = s;
#pragma unroll
            for (int off = 32; off; off >>= 1) mx = fmaxf(mx, __shfl_xor(mx, off));
            float e = __expf(s - mx), sum = e;
#pragma unroll
            for (int off = 32; off; off >>= 1) sum += __shfl_xor(sum, off);
            float a = e / sum;
            unsigned hb = f2bf(a);
            sch[lane] = (unsigned short)hb;
            scl[lane] = (unsigned short)f2bf(a - blo(hb));
        }
        __syncthreads();

        // ---- gates = sum_t alpha_t * G3T[b][:,t]  via MFMA (K=64)
        {
            const unsigned short* ab = ((lane & 8) == 0) ? sch : scl;
            bfrag aA = *(const bfrag*)&ab[quad * 8];
            bfrag aB = *(const bfrag*)&ab[32 + quad * 8];
            const unsigned short* gp = G3s + (size_t)b * G3_BLK_S
                                     + ((size_t)(wv * 96) + col) * 64 + quad * 8;
            ffrag g[6];
#pragma unroll
            for (int t6 = 0; t6 < 6; ++t6) {
                g[t6][0] = 0.0f; g[t6][1] = 0.0f; g[t6][2] = 0.0f; g[t6][3] = 0.0f;
            }
#pragma unroll
            for (int t6 = 0; t6 < 6; ++t6) {
                bfrag w0 = *(const bfrag*)(gp + t6 * 1024);
                g[t6] = __builtin_amdgcn_mfma_f32_16x16x32_bf16(aA, w0, g[t6], 0, 0, 0);
            }
#pragma unroll
            for (int t6 = 0; t6 < 6; ++t6) {
                bfrag w1 = *(const bfrag*)(gp + t6 * 1024 + 32);
                g[t6] = __builtin_amdgcn_mfma_f32_16x16x32_bf16(aB, w1, g[t6], 0, 0, 0);
            }
#pragma unroll
            for (int t6 = 0; t6 < 6; ++t6) {
                float s = g[t6][0] + __shfl_xor(g[t6][0], 32);
                if (lane < 16) gates3[(wv * 6 + t6) * 16 + lane] = s;
            }
        }
        __syncthreads();

        // ---- gate math -> hm (+ hi/lo pack for next step's GEMV1)
        if (tid < 512) {
            const size_t m = (size_t)k * 128 + b;
            float gi = gates3[tid]        + ntload(&pre_m_h[(m * 3 + 0) * 512 + tid]);
            float gg = gates3[512 + tid]  + ntload(&pre_m_h[(m * 3 + 1) * 512 + tid]);
            float go = gates3[1024 + tid] + ntload(&pre_m_h[(m * 3 + 2) * 512 + tid]);
            float cc = fast_sigmoid(gi) * fast_tanh(gg);
            float hv = fast_sigmoid(go) * fast_tanh(cc);
            hm[tid] = hv;
            unsigned hb = f2bf(hv);
            hmh[tid] = (unsigned short)hb;
            hml[tid] = (unsigned short)f2bf(hv - blo(hb));
        }
        __syncthreads();
    }

    if (wv < 3) {
        float p = 0.0f;
#pragma unroll
        for (int u = 0; u < 8; ++u) {
            int h = lane + 64 * u;
            p += hm[h] * fc_w[wv * 512 + h];
        }
#pragma unroll
        for (int off = 32; off; off >>= 1) p += __shfl_xor(p, off);
        if (lane == 0) out[b * 3 + wv] = p + fc_b[wv];
    }
}

extern "C" void kernel_launch(void* const* d_in, const int* in_sizes, int n_in,
                              void* d_out, int out_size, void* d_ws, size_t ws_size,
                              hipStream_t stream)
{
    (void)in_sizes; (void)n_in; (void)out_size;
    const int*   premise    = (const int*)d_in[0];
    const int*   hypothesis = (const int*)d_in[2];
    const float* embed  = (const float*)d_in[4];
    const float* w_e    = (const float*)d_in[5];
    const float* Ws     = (const float*)d_in[6];
    const float* Wt     = (const float*)d_in[7];
    const float* Wm     = (const float*)d_in[8];
    const float* Wih_p  = (const float*)d_in[9];
    const float* bih_p  = (const float*)d_in[10];
    const float* bhh_p  = (const float*)d_in[11];
    const float* Wih_h  = (const float*)d_in[12];
    const float* bih_h  = (const float*)d_in[13];
    const float* bhh_h  = (const float*)d_in[14];
    const float* Wih_m  = (const float*)d_in[15];
    const float* bih_m  = (const float*)d_in[16];
    const float* bhh_m  = (const float*)d_in[17];
    const float* fc_w   = (const float*)d_in[18];
    const float* fc_b   = (const float*)d_in[19];

    // Workspace layout (floats), total 29,425,664 <= guard 29,556,736:
    //   RhB     @ 0         : 2,097,152  (bf16 hi/lo A-frags; WmB aliases)
    //   pre_s   @ 2,097,152 : 4,194,304
    //   pre_t   @ 6,291,456 : 4,194,304
    //   pre_m_h @10,485,760 :12,582,912  (halves also = encoder preact P)
    //   G3      @23,068,672 : 6,356,992  (bf16 t-major, 194KB/block padded)
    float* ws      = (float*)d_ws;
    unsigned short* RhB = (unsigned short*)ws;
    const uint4* RhB4   = (const uint4*)ws;
    float* pre_s   = ws + 2097152;
    float* pre_t   = ws + 6291456;
    float* pre_m_h = ws + 10485760;
    unsigned short* G3s = (unsigned short*)(ws + 23068672);
    unsigned* WmB  = (unsigned*)ws;           // aliases RhB after last reader
    float* outp    = (float*)d_out;
    if (ws_size < (size_t)29556736 * 4) return;

    dim3 blk(256);

    // ---- Phase A: premise halves -> RhB(half) -> pre_s(half), G3(half)
    for (int h = 0; h < 2; ++h) {
        float* P = pre_m_h + (size_t)h * 6291456;
        g3_gather_kernel<<<dim3(16, 24), blk, 0, stream>>>(
            embed, premise + h * 4096, 300, 300, Wih_p, 300, bih_p, bhh_p, P);
        enc_pack_kernel<<<2048, blk, 0, stream>>>(P, RhB);
        mfma_nt_kernel<<<dim3(16, 8), blk, 0, stream>>>(
            RhB4, Ws, pre_s + (size_t)h * 2097152);
        g3pack_kernel<<<dim3(16, 24), blk, 0, stream>>>(
            RhB4, Wih_m, G3s, h * 4096);
    }
    // ---- Phase A: hypothesis halves -> RhB(half) -> pre_t(half), pre_m_h(half)
    for (int h = 0; h < 2; ++h) {
        float* P = pre_m_h + (size_t)h * 6291456;
        g3_gather_kernel<<<dim3(16, 24), blk, 0, stream>>>(
            embed, hypothesis + h * 4096, 300, 300, Wih_h, 300, bih_h, bhh_h, P);
        enc_pack_kernel<<<2048, blk, 0, stream>>>(P, RhB);
        mfma_nt_kernel<<<dim3(16, 8), blk, 0, stream>>>(
            RhB4, Wt, pre_t + (size_t)h * 2097152);
        g3_packedA_kernel<<<dim3(16, 24), blk, 0, stream>>>(
            RhB4, Wih_m + 512, 1024, bih_m, bhh_m,
            pre_m_h + (size_t)h * 6291456);
    }

    // ---- Wm pack (after RhB's last reader; output aliases RhB)
    pack_wm_kernel<<<512, blk, 0, stream>>>(Wm, WmB);

    // ---- Phase B (128KB dynamic LDS for pre_s cache)
    static int attr_done = 0;
    if (!attr_done) {
        hipFuncSetAttribute((const void*)phaseB_kernel,
                            hipFuncAttributeMaxDynamicSharedMemorySize, 131072);
        attr_done = 1;
    }
    phaseB_kernel<<<dim3(128), dim3(1024), 131072, stream>>>(
        pre_s, pre_t, pre_m_h, WmB, G3s, w_e, fc_w, fc_b, outp);
}

// Round 13
// 1390.089 us; speedup vs baseline: 1.3351x; 1.0303x over previous
//
#include <hip/hip_runtime.h>

// MatchLSTM forward (Round 28): phase-A grid/occupancy fix.
//   R27 post-mortem: phase A ~685us at ~5% of MFMA peak. Wave audit:
//   mfma_nt grid (16,8)=128 blocks x 4 waves on 256 CUs -> HALF THE GPU
//   IDLE; g3 kernels (16,24)=384 blocks -> 2-vs-1 blocks/CU imbalance
//   (1.3x tail stretch). R28: 2-WAVE (128-thread) BLOCKS, block M = 128:
//   nt -> (32,8)=256 blocks (1/CU uniform), g3s -> (32,24)=768 (3/CU
//   uniform). Per-wave inner loop / MFMA order / outputs untouched ->
//   BIT-IDENTICAL (absmax must stay 0.0009765625). launch_bounds(128,2)
//   keeps the same 128-VGPR cap -> same per-wave codegen.
// phaseB: R25 verbatim (747us stable). enc_pack/pack_wm unchanged.

#define DEV static __device__ __forceinline__

DEV float fast_sigmoid(float x) { return 1.0f / (1.0f + __expf(-x)); }
DEV float fast_tanh(float x)    { return 1.0f - 2.0f / (__expf(2.0f * x) + 1.0f); }

DEV unsigned f2bf(float x) {
    unsigned v = __float_as_uint(x);
    return (v + 0x7FFFu + ((v >> 16) & 1u)) >> 16;
}
DEV float blo(unsigned u) { return __uint_as_float(u << 16); }

DEV float ntload(const float* p) { return __builtin_nontemporal_load(p); }

typedef __attribute__((ext_vector_type(8))) short bfrag;   // 8 bf16
typedef __attribute__((ext_vector_type(4))) float ffrag;   // 4 fp32 acc

// G3 block region (ushorts): 1536*64 data + 1024 pad = 99328 = 194KB
#define G3_BLK_S 99328

DEV void cvt_hilo(const float* v, bfrag& hi, bfrag& lo)
{
#pragma unroll
    for (int z = 0; z < 8; ++z) {
        unsigned h = f2bf(v[z]);
        hi[z] = (short)h;
        lo[z] = (short)f2bf(v[z] - __uint_as_float(h << 16));
    }
}

// ---------------------------------------------------------------------------
// MFMA GEMM (R28: 2-wave blocks): C = A_packed . W^T, wave = 64M x 64N.
// ---------------------------------------------------------------------------
__global__ __launch_bounds__(128, 2) void mfma_nt_kernel(
    const uint4* __restrict__ AB, const float* __restrict__ W,
    float* __restrict__ C)
{
    const int wv   = threadIdx.x >> 6;
    const int lane = threadIdx.x & 63;
    const int row  = lane & 15;
    const int quad = lane >> 4;
    const int m0 = blockIdx.x * 128 + wv * 64;
    const int n0 = blockIdx.y * 64;
    const int mt0 = m0 >> 4;                       // first of 4 m-tiles

    ffrag acc[4][4];
#pragma unroll
    for (int mt = 0; mt < 4; ++mt)
#pragma unroll
        for (int n = 0; n < 4; ++n)
#pragma unroll
            for (int r = 0; r < 4; ++r) acc[mt][n][r] = 0.0f;

#pragma unroll 1
    for (int k0 = 0; k0 < 512; k0 += 32) {
        const int kc = k0 >> 5;
        bfrag ahi[4], alo[4];
#pragma unroll
        for (int mt = 0; mt < 4; ++mt) {
            const uint4* ap = AB + ((size_t)(kc * 256 + mt0 + mt) * 64 + lane) * 2;
            ahi[mt] = *(const bfrag*)(ap);
            alo[mt] = *(const bfrag*)(ap + 1);
        }
#pragma unroll
        for (int n = 0; n < 4; ++n) {
            const float* wp = W + (size_t)(n0 + n * 16 + row) * 512 + k0 + quad * 8;
            float4 wA = *(const float4*)wp;
            float4 wB = *(const float4*)(wp + 4);
            float wvv[8] = {wA.x, wA.y, wA.z, wA.w, wB.x, wB.y, wB.z, wB.w};
            bfrag whi, wlo;
            cvt_hilo(wvv, whi, wlo);
#pragma unroll
            for (int mt = 0; mt < 4; ++mt) {
                acc[mt][n] = __builtin_amdgcn_mfma_f32_16x16x32_bf16(ahi[mt], whi, acc[mt][n], 0, 0, 0);
                acc[mt][n] = __builtin_amdgcn_mfma_f32_16x16x32_bf16(alo[mt], whi, acc[mt][n], 0, 0, 0);
                acc[mt][n] = __builtin_amdgcn_mfma_f32_16x16x32_bf16(ahi[mt], wlo, acc[mt][n], 0, 0, 0);
            }
        }
    }
#pragma unroll
    for (int mt = 0; mt < 4; ++mt)
#pragma unroll
        for (int n = 0; n < 4; ++n)
#pragma unroll
            for (int r = 0; r < 4; ++r)
                C[(size_t)(m0 + mt * 16 + quad * 4 + r) * 512 + n0 + n * 16 + row]
                    = acc[mt][n][r];
}

// ---------------------------------------------------------------------------
// Gather 3-gate GEMM (R28: 2-wave blocks): fp32 A from embed, K=300.
// ---------------------------------------------------------------------------
__global__ __launch_bounds__(128, 2) void g3_gather_kernel(
    const float* __restrict__ A, const int* __restrict__ gidx,
    int lda, int K,
    const float* __restrict__ W, int ldw,
    const float* __restrict__ bias1, const float* __restrict__ bias2,
    float* __restrict__ out)
{
    const int wv   = threadIdx.x >> 6;
    const int lane = threadIdx.x & 63;
    const int row  = lane & 15;
    const int quad = lane >> 4;
    const int m0   = blockIdx.x * 128 + wv * 64;
    const int gate = blockIdx.y >> 3;
    const int gbase = (gate == 0) ? 0 : (gate == 1 ? 1024 : 1536);
    const int j0   = (blockIdx.y & 7) * 64;

    int arow[4];
#pragma unroll
    for (int mt = 0; mt < 4; ++mt)
        arow[mt] = gidx[m0 + mt * 16 + row];

    ffrag acc[4][4];
#pragma unroll
    for (int mt = 0; mt < 4; ++mt)
#pragma unroll
        for (int n = 0; n < 4; ++n)
#pragma unroll
            for (int r = 0; r < 4; ++r) acc[mt][n][r] = 0.0f;

#pragma unroll 1
    for (int k0 = 0; k0 < K; k0 += 32) {
        const bool tail = (k0 + 32 > K);
        bfrag ahi[4], alo[4];
#pragma unroll
        for (int mt = 0; mt < 4; ++mt) {
            float av[8];
            if (!tail) {
                const float* ap = A + (size_t)arow[mt] * lda + k0 + quad * 8;
                float4 aA = *(const float4*)ap;
                float4 aB = *(const float4*)(ap + 4);
                av[0]=aA.x; av[1]=aA.y; av[2]=aA.z; av[3]=aA.w;
                av[4]=aB.x; av[5]=aB.y; av[6]=aB.z; av[7]=aB.w;
            } else {
#pragma unroll
                for (int z = 0; z < 8; ++z) {
                    int kk = k0 + quad * 8 + z;
                    av[z] = (kk < K) ? A[(size_t)arow[mt] * lda + kk] : 0.0f;
                }
            }
            cvt_hilo(av, ahi[mt], alo[mt]);
        }
#pragma unroll
        for (int n = 0; n < 4; ++n) {
            const int wrow = gbase + j0 + n * 16 + row;
            float wvv[8];
            if (!tail) {
                const float* wp = W + (size_t)wrow * ldw + k0 + quad * 8;
                float4 wA = *(const float4*)wp;
                float4 wB = *(const float4*)(wp + 4);
                wvv[0]=wA.x; wvv[1]=wA.y; wvv[2]=wA.z; wvv[3]=wA.w;
                wvv[4]=wB.x; wvv[5]=wB.y; wvv[6]=wB.z; wvv[7]=wB.w;
            } else {
#pragma unroll
                for (int z = 0; z < 8; ++z) {
                    int kk = k0 + quad * 8 + z;
                    wvv[z] = (kk < K) ? W[(size_t)wrow * ldw + kk] : 0.0f;
                }
            }
            bfrag whi, wlo;
            cvt_hilo(wvv, whi, wlo);
#pragma unroll
            for (int mt = 0; mt < 4; ++mt) {
                acc[mt][n] = __builtin_amdgcn_mfma_f32_16x16x32_bf16(ahi[mt], whi, acc[mt][n], 0, 0, 0);
                acc[mt][n] = __builtin_amdgcn_mfma_f32_16x16x32_bf16(alo[mt], whi, acc[mt][n], 0, 0, 0);
                acc[mt][n] = __builtin_amdgcn_mfma_f32_16x16x32_bf16(ahi[mt], wlo, acc[mt][n], 0, 0, 0);
            }
        }
    }
#pragma unroll
    for (int n = 0; n < 4; ++n) {
        const int j = j0 + n * 16 + row;
        const float bb = bias1[gbase + j] + bias2[gbase + j];
#pragma unroll
        for (int mt = 0; mt < 4; ++mt)
#pragma unroll
            for (int r = 0; r < 4; ++r) {
                const int m = m0 + mt * 16 + quad * 4 + r;
                out[((size_t)m * 3 + gate) * 512 + j] = acc[mt][n][r] + bb;
            }
    }
}

// ---------------------------------------------------------------------------
// 3-gate GEMM, packed A (R28: 2-wave blocks): K=512; fp32 out + biases.
// ---------------------------------------------------------------------------
__global__ __launch_bounds__(128, 2) void g3_packedA_kernel(
    const uint4* __restrict__ AB,
    const float* __restrict__ W, int ldw,
    const float* __restrict__ bias1, const float* __restrict__ bias2,
    float* __restrict__ out)
{
    const int wv   = threadIdx.x >> 6;
    const int lane = threadIdx.x & 63;
    const int row  = lane & 15;
    const int quad = lane >> 4;
    const int m0   = blockIdx.x * 128 + wv * 64;
    const int gate = blockIdx.y >> 3;
    const int gbase = (gate == 0) ? 0 : (gate == 1 ? 1024 : 1536);
    const int j0   = (blockIdx.y & 7) * 64;
    const int mt0  = m0 >> 4;

    ffrag acc[4][4];
#pragma unroll
    for (int mt = 0; mt < 4; ++mt)
#pragma unroll
        for (int n = 0; n < 4; ++n)
#pragma unroll
            for (int r = 0; r < 4; ++r) acc[mt][n][r] = 0.0f;

#pragma unroll 1
    for (int k0 = 0; k0 < 512; k0 += 32) {
        const int kc = k0 >> 5;
        bfrag ahi[4], alo[4];
#pragma unroll
        for (int mt = 0; mt < 4; ++mt) {
            const uint4* ap = AB + ((size_t)(kc * 256 + mt0 + mt) * 64 + lane) * 2;
            ahi[mt] = *(const bfrag*)(ap);
            alo[mt] = *(const bfrag*)(ap + 1);
        }
#pragma unroll
        for (int n = 0; n < 4; ++n) {
            const int wrow = gbase + j0 + n * 16 + row;
            const float* wp = W + (size_t)wrow * ldw + k0 + quad * 8;
            float4 wA = *(const float4*)wp;
            float4 wB = *(const float4*)(wp + 4);
            float wvv[8] = {wA.x, wA.y, wA.z, wA.w, wB.x, wB.y, wB.z, wB.w};
            bfrag whi, wlo;
            cvt_hilo(wvv, whi, wlo);
#pragma unroll
            for (int mt = 0; mt < 4; ++mt) {
                acc[mt][n] = __builtin_amdgcn_mfma_f32_16x16x32_bf16(ahi[mt], whi, acc[mt][n], 0, 0, 0);
                acc[mt][n] = __builtin_amdgcn_mfma_f32_16x16x32_bf16(alo[mt], whi, acc[mt][n], 0, 0, 0);
                acc[mt][n] = __builtin_amdgcn_mfma_f32_16x16x32_bf16(ahi[mt], wlo, acc[mt][n], 0, 0, 0);
            }
        }
    }
#pragma unroll
    for (int n = 0; n < 4; ++n) {
        const int j = j0 + n * 16 + row;
        const float bb = bias1[gbase + j] + bias2[gbase + j];
#pragma unroll
        for (int mt = 0; mt < 4; ++mt)
#pragma unroll
            for (int r = 0; r < 4; ++r) {
                const int m = m0 + mt * 16 + quad * 4 + r;
                out[((size_t)m * 3 + gate) * 512 + j] = acc[mt][n][r] + bb;
            }
    }
}

// ---------------------------------------------------------------------------
// G3 GEMM (R28: 2-wave blocks): packed A; t-major G3 output (R25 layout).
// ---------------------------------------------------------------------------
__global__ __launch_bounds__(128, 2) void g3pack_kernel(
    const uint4* __restrict__ AB,
    const float* __restrict__ W,            // Wih_m, ldw 1024
    unsigned short* __restrict__ G3s,
    int mbase)                              // 0 or 4096
{
    const int wv   = threadIdx.x >> 6;
    const int lane = threadIdx.x & 63;
    const int row  = lane & 15;
    const int quad = lane >> 4;
    const int m0   = blockIdx.x * 128 + wv * 64;
    const int gate = blockIdx.y >> 3;
    const int gbase = (gate == 0) ? 0 : (gate == 1 ? 1024 : 1536);
    const int j0   = (blockIdx.y & 7) * 64;
    const int mt0  = m0 >> 4;

    ffrag acc[4][4];
#pragma unroll
    for (int mt = 0; mt < 4; ++mt)
#pragma unroll
        for (int n = 0; n < 4; ++n)
#pragma unroll
            for (int r = 0; r < 4; ++r) acc[mt][n][r] = 0.0f;

#pragma unroll 1
    for (int k0 = 0; k0 < 512; k0 += 32) {
        const int kc = k0 >> 5;
        bfrag ahi[4], alo[4];
#pragma unroll
        for (int mt = 0; mt < 4; ++mt) {
            const uint4* ap = AB + ((size_t)(kc * 256 + mt0 + mt) * 64 + lane) * 2;
            ahi[mt] = *(const bfrag*)(ap);
            alo[mt] = *(const bfrag*)(ap + 1);
        }
#pragma unroll
        for (int n = 0; n < 4; ++n) {
            const int wrow = gbase + j0 + n * 16 + row;
            const float* wp = W + (size_t)wrow * 1024 + k0 + quad * 8;
            float4 wA = *(const float4*)wp;
            float4 wB = *(const float4*)(wp + 4);
            float wvv[8] = {wA.x, wA.y, wA.z, wA.w, wB.x, wB.y, wB.z, wB.w};
            bfrag whi, wlo;
            cvt_hilo(wvv, whi, wlo);
#pragma unroll
            for (int mt = 0; mt < 4; ++mt) {
                acc[mt][n] = __builtin_amdgcn_mfma_f32_16x16x32_bf16(ahi[mt], whi, acc[mt][n], 0, 0, 0);
                acc[mt][n] = __builtin_amdgcn_mfma_f32_16x16x32_bf16(alo[mt], whi, acc[mt][n], 0, 0, 0);
                acc[mt][n] = __builtin_amdgcn_mfma_f32_16x16x32_bf16(ahi[mt], wlo, acc[mt][n], 0, 0, 0);
            }
        }
    }
#pragma unroll
    for (int n = 0; n < 4; ++n) {
        const int j = j0 + n * 16 + row;
#pragma unroll
        for (int mt = 0; mt < 4; ++mt)
#pragma unroll
            for (int r = 0; r < 4; ++r) {
                const int mg = mbase + m0 + mt * 16 + quad * 4 + r;
                const int t = mg >> 7, b = mg & 127;
                size_t idx = (size_t)b * G3_BLK_S
                           + ((size_t)(gate * 512 + j)) * 64 + t;
                G3s[idx] = (unsigned short)f2bf(acc[mt][n][r]);
            }
    }
}

// ---------------------------------------------------------------------------
// Encoder gate math + A-frag pack (validated R27).
// ---------------------------------------------------------------------------
__global__ __launch_bounds__(256) void enc_pack_kernel(
    const float* __restrict__ P, unsigned short* __restrict__ RhB)
{
    const int i = blockIdx.x * 256 + threadIdx.x;     // 0 .. 524287
    const int m = i >> 7;
    const int j4 = (i & 127) * 4;
    const float* p = P + (size_t)m * 1536 + j4;
    float4 gi = *(const float4*)p;
    float4 gg = *(const float4*)(p + 512);
    float4 go = *(const float4*)(p + 1024);
    float r[4];
    r[0] = fast_sigmoid(go.x) * fast_tanh(fast_sigmoid(gi.x) * fast_tanh(gg.x));
    r[1] = fast_sigmoid(go.y) * fast_tanh(fast_sigmoid(gi.y) * fast_tanh(gg.y));
    r[2] = fast_sigmoid(go.z) * fast_tanh(fast_sigmoid(gi.z) * fast_tanh(gg.z));
    r[3] = fast_sigmoid(go.w) * fast_tanh(fast_sigmoid(gi.w) * fast_tanh(gg.w));

    const int mt   = m >> 4;
    const int lane = (((j4 >> 3) & 3) << 4) + (m & 15);
    const int kc   = j4 >> 5;
    const int z0   = j4 & 7;                           // 0 or 4
    unsigned short* hi = RhB + ((size_t)(kc * 256 + mt) * 64 + lane) * 16 + z0;
    unsigned short* lo = hi + 8;
#pragma unroll
    for (int t = 0; t < 4; ++t) {
        unsigned hb = f2bf(r[t]);
        hi[t] = (unsigned short)hb;
        lo[t] = (unsigned short)f2bf(r[t] - blo(hb));
    }
}

// ---------------------------------------------------------------------------
// Wm pack (validated R19): [kc][nt][lane] tile-interleaved.
// ---------------------------------------------------------------------------
__global__ __launch_bounds__(256) void pack_wm_kernel(
    const float* __restrict__ Wm, unsigned* __restrict__ WmB)
{
    int i = blockIdx.x * 256 + threadIdx.x;           // 0 .. 131071
    int u = i & 3, lane = (i >> 2) & 63;
    int nt = (i >> 8) & 31, kc = i >> 13;
    int row = nt * 16 + (lane & 15);
    int k = kc * 32 + ((lane >> 4) << 3) + u * 2;
    unsigned lo = f2bf(Wm[(size_t)row * 512 + k]);
    unsigned hi = f2bf(Wm[(size_t)row * 512 + k + 1]);
    WmB[i] = lo | (hi << 16);
}

// ---------------------------------------------------------------------------
// Phase B (R25 verbatim): GEMV1 K-split + MFMA G3-sum (t-major).
// ---------------------------------------------------------------------------
__global__ __launch_bounds__(1024) void phaseB_kernel(
    const float* __restrict__ pre_s, const float* __restrict__ pre_t,
    const float* __restrict__ pre_m_h,
    const unsigned* __restrict__ WmB, const unsigned short* __restrict__ G3s,
    const float* __restrict__ w_e,
    const float* __restrict__ fc_w,  const float* __restrict__ fc_b,
    float* __restrict__ out)
{
    extern __shared__ __align__(16) float psL[];      // 64*512 fp32 = 128KB
    __shared__ __align__(16) float hm[512];
    __shared__ __align__(16) float base[512];
    __shared__ __align__(16) float wesh[512];
    __shared__ __align__(16) float sc[64];
    __shared__ __align__(16) float red[2 * 512];
    __shared__ __align__(16) float gates3[1536];
    __shared__ __align__(16) unsigned short hmh[512];
    __shared__ __align__(16) unsigned short hml[512];
    __shared__ __align__(16) unsigned short sch[64];
    __shared__ __align__(16) unsigned short scl[64];

    const int b    = blockIdx.x;
    const int tid  = threadIdx.x;
    const int wv   = tid >> 6;
    const int lane = tid & 63;
    const int col  = lane & 15;
    const int quad = lane >> 4;

    if (tid < 512) {
        wesh[tid] = w_e[tid];
        hm[tid] = 0.0f; hmh[tid] = 0; hml[tid] = 0;
    }
    for (int i = tid; i < 32768; i += 1024) {
        int t = i >> 9, h = i & 511;
        psL[i] = ntload(&pre_s[((size_t)t * 128 + b) * 512 + h]);
    }
    __syncthreads();

    for (int k = 0; k < 64; ++k) {
        // ---- GEMV1 (K-split): partials for base = Wm . hm
        {
            const int kh2 = wv >> 3;
            const int tp  = (wv & 7) * 4;
            ffrag a0 = {0.0f,0.0f,0.0f,0.0f}, a1 = {0.0f,0.0f,0.0f,0.0f};
            ffrag a2 = {0.0f,0.0f,0.0f,0.0f}, a3 = {0.0f,0.0f,0.0f,0.0f};
            const uint4* wp = (const uint4*)WmB
                            + ((size_t)(kh2 * 8) * 32 + tp) * 64 + lane;
            const unsigned short* ab = ((lane & 8) == 0) ? hmh : hml;
#pragma unroll 1
            for (int kc = 0; kc < 8; ++kc) {
                bfrag a  = *(const bfrag*)&ab[(kh2 * 8 + kc) * 32 + quad * 8];
                bfrag w0 = *(const bfrag*)(wp);
                bfrag w1 = *(const bfrag*)(wp + 64);
                bfrag w2 = *(const bfrag*)(wp + 128);
                bfrag w3 = *(const bfrag*)(wp + 192);
                a0 = __builtin_amdgcn_mfma_f32_16x16x32_bf16(a, w0, a0, 0, 0, 0);
                a1 = __builtin_amdgcn_mfma_f32_16x16x32_bf16(a, w1, a1, 0, 0, 0);
                a2 = __builtin_amdgcn_mfma_f32_16x16x32_bf16(a, w2, a2, 0, 0, 0);
                a3 = __builtin_amdgcn_mfma_f32_16x16x32_bf16(a, w3, a3, 0, 0, 0);
                wp += 2048;
            }
            float s0 = a0[0] + __shfl_xor(a0[0], 32);
            float s1 = a1[0] + __shfl_xor(a1[0], 32);
            float s2 = a2[0] + __shfl_xor(a2[0], 32);
            float s3 = a3[0] + __shfl_xor(a3[0], 32);
            if (lane < 16) {
                float* rr = &red[kh2 * 512];
                rr[(tp + 0) * 16 + lane] = s0;
                rr[(tp + 1) * 16 + lane] = s1;
                rr[(tp + 2) * 16 + lane] = s2;
                rr[(tp + 3) * 16 + lane] = s3;
            }
        }
        __syncthreads();
        if (tid < 512)
            base[tid] = red[tid] + red[512 + tid]
                      + ntload(&pre_t[((size_t)k * 128 + b) * 512 + tid]);
        __syncthreads();

        // ---- attention scores: e[t] = w_e . tanh(psL[t] + base)  (all LDS)
#pragma unroll
        for (int tt = 0; tt < 4; ++tt) {
            int t = wv * 4 + tt;
            const float* ps = &psL[t * 512];
            float p = 0.0f;
#pragma unroll
            for (int u = 0; u < 8; ++u) {
                int h = lane + 64 * u;
                p += wesh[h] * fast_tanh(ps[h] + base[h]);
            }
#pragma unroll
            for (int off = 32; off; off >>= 1) p += __shfl_xor(p, off);
            if (lane == 0) sc[t] = p;
        }
        __syncthreads();

        // ---- softmax (+ bf16 hi/lo pack of alpha)
        if (wv == 0) {
            float s = sc[lane], mx = s;
#pragma unroll
            for (int off = 32; off; off >>= 1) mx = fmaxf(mx, __shfl_xor(mx, off));
            float e = __expf(s - mx), sum = e;
#pragma unroll
            for (int off = 32; off; off >>= 1) sum += __shfl_xor(sum, off);
            float a = e / sum;
            unsigned hb = f2bf(a);
            sch[lane] = (unsigned short)hb;
            scl[lane] = (unsigned short)f2bf(a - blo(hb));
        }
        __syncthreads();

        // ---- gates = sum_t alpha_t * G3T[b][:,t]  via MFMA (K=64)
        {
            const unsigned short* ab = ((lane & 8) == 0) ? sch : scl;
            bfrag aA = *(const bfrag*)&ab[quad * 8];
            bfrag aB = *(const bfrag*)&ab[32 + quad * 8];
            const unsigned short* gp = G3s + (size_t)b * G3_BLK_S
                                     + ((size_t)(wv * 96) + col) * 64 + quad * 8;
            ffrag g[6];
#pragma unroll
            for (int t6 = 0; t6 < 6; ++t6) {
                g[t6][0] = 0.0f; g[t6][1] = 0.0f; g[t6][2] = 0.0f; g[t6][3] = 0.0f;
            }
#pragma unroll
            for (int t6 = 0; t6 < 6; ++t6) {
                bfrag w0 = *(const bfrag*)(gp + t6 * 1024);
                g[t6] = __builtin_amdgcn_mfma_f32_16x16x32_bf16(aA, w0, g[t6], 0, 0, 0);
            }
#pragma unroll
            for (int t6 = 0; t6 < 6; ++t6) {
                bfrag w1 = *(const bfrag*)(gp + t6 * 1024 + 32);
                g[t6] = __builtin_amdgcn_mfma_f32_16x16x32_bf16(aB, w1, g[t6], 0, 0, 0);
            }
#pragma unroll
            for (int t6 = 0; t6 < 6; ++t6) {
                float s = g[t6][0] + __shfl_xor(g[t6][0], 32);
                if (lane < 16) gates3[(wv * 6 + t6) * 16 + lane] = s;
            }
        }
        __syncthreads();

        // ---- gate math -> hm (+ hi/lo pack for next step's GEMV1)
        if (tid < 512) {
            const size_t m = (size_t)k * 128 + b;
            float gi = gates3[tid]        + ntload(&pre_m_h[(m * 3 + 0) * 512 + tid]);
            float gg = gates3[512 + tid]  + ntload(&pre_m_h[(m * 3 + 1) * 512 + tid]);
            float go = gates3[1024 + tid] + ntload(&pre_m_h[(m * 3 + 2) * 512 + tid]);
            float cc = fast_sigmoid(gi) * fast_tanh(gg);
            float hv = fast_sigmoid(go) * fast_tanh(cc);
            hm[tid] = hv;
            unsigned hb = f2bf(hv);
            hmh[tid] = (unsigned short)hb;
            hml[tid] = (unsigned short)f2bf(hv - blo(hb));
        }
        __syncthreads();
    }

    if (wv < 3) {
        float p = 0.0f;
#pragma unroll
        for (int u = 0; u < 8; ++u) {
            int h = lane + 64 * u;
            p += hm[h] * fc_w[wv * 512 + h];
        }
#pragma unroll
        for (int off = 32; off; off >>= 1) p += __shfl_xor(p, off);
        if (lane == 0) out[b * 3 + wv] = p + fc_b[wv];
    }
}

extern "C" void kernel_launch(void* const* d_in, const int* in_sizes, int n_in,
                              void* d_out, int out_size, void* d_ws, size_t ws_size,
                              hipStream_t stream)
{
    (void)in_sizes; (void)n_in; (void)out_size;
    const int*   premise    = (const int*)d_in[0];
    const int*   hypothesis = (const int*)d_in[2];
    const float* embed  = (const float*)d_in[4];
    const float* w_e    = (const float*)d_in[5];
    const float* Ws     = (const float*)d_in[6];
    const float* Wt     = (const float*)d_in[7];
    const float* Wm     = (const float*)d_in[8];
    const float* Wih_p  = (const float*)d_in[9];
    const float* bih_p  = (const float*)d_in[10];
    const float* bhh_p  = (const float*)d_in[11];
    const float* Wih_h  = (const float*)d_in[12];
    const float* bih_h  = (const float*)d_in[13];
    const float* bhh_h  = (const float*)d_in[14];
    const float* Wih_m  = (const float*)d_in[15];
    const float* bih_m  = (const float*)d_in[16];
    const float* bhh_m  = (const float*)d_in[17];
    const float* fc_w   = (const float*)d_in[18];
    const float* fc_b   = (const float*)d_in[19];

    // Workspace layout (floats), total 29,425,664 <= guard 29,556,736:
    //   RhB     @ 0         : 2,097,152  (bf16 hi/lo A-frags; WmB aliases)
    //   pre_s   @ 2,097,152 : 4,194,304
    //   pre_t   @ 6,291,456 : 4,194,304
    //   pre_m_h @10,485,760 :12,582,912  (halves also = encoder preact P)
    //   G3      @23,068,672 : 6,356,992  (bf16 t-major, 194KB/block padded)
    float* ws      = (float*)d_ws;
    unsigned short* RhB = (unsigned short*)ws;
    const uint4* RhB4   = (const uint4*)ws;
    float* pre_s   = ws + 2097152;
    float* pre_t   = ws + 6291456;
    float* pre_m_h = ws + 10485760;
    unsigned short* G3s = (unsigned short*)(ws + 23068672);
    unsigned* WmB  = (unsigned*)ws;           // aliases RhB after last reader
    float* outp    = (float*)d_out;
    if (ws_size < (size_t)29556736 * 4) return;

    dim3 blk2(128);
    dim3 blk(256);

    // ---- Phase A: premise halves -> RhB(half) -> pre_s(half), G3(half)
    for (int h = 0; h < 2; ++h) {
        float* P = pre_m_h + (size_t)h * 6291456;
        g3_gather_kernel<<<dim3(32, 24), blk2, 0, stream>>>(
            embed, premise + h * 4096, 300, 300, Wih_p, 300, bih_p, bhh_p, P);
        enc_pack_kernel<<<2048, blk, 0, stream>>>(P, RhB);
        mfma_nt_kernel<<<dim3(32, 8), blk2, 0, stream>>>(
            RhB4, Ws, pre_s + (size_t)h * 2097152);
        g3pack_kernel<<<dim3(32, 24), blk2, 0, stream>>>(
            RhB4, Wih_m, G3s, h * 4096);
    }
    // ---- Phase A: hypothesis halves -> RhB(half) -> pre_t(half), pre_m_h(half)
    for (int h = 0; h < 2; ++h) {
        float* P = pre_m_h + (size_t)h * 6291456;
        g3_gather_kernel<<<dim3(32, 24), blk2, 0, stream>>>(
            embed, hypothesis + h * 4096, 300, 300, Wih_h, 300, bih_h, bhh_h, P);
        enc_pack_kernel<<<2048, blk, 0, stream>>>(P, RhB);
        mfma_nt_kernel<<<dim3(32, 8), blk2, 0, stream>>>(
            RhB4, Wt, pre_t + (size_t)h * 2097152);
        g3_packedA_kernel<<<dim3(32, 24), blk2, 0, stream>>>(
            RhB4, Wih_m + 512, 1024, bih_m, bhh_m,
            pre_m_h + (size_t)h * 6291456);
    }

    // ---- Wm pack (after RhB's last reader; output aliases RhB)
    pack_wm_kernel<<<512, blk, 0, stream>>>(Wm, WmB);

    // ---- Phase B (128KB dynamic LDS for pre_s cache)
    static int attr_done = 0;
    if (!attr_done) {
        hipFuncSetAttribute((const void*)phaseB_kernel,
                            hipFuncAttributeMaxDynamicSharedMemorySize, 131072);
        attr_done = 1;
    }
    phaseB_kernel<<<dim3(128), dim3(1024), 131072, stream>>>(
        pre_s, pre_t, pre_m_h, WmB, G3s, w_e, fc_w, fc_b, outp);
}

// Round 14
// 1316.095 us; speedup vs baseline: 1.4102x; 1.0562x over previous
//
#include <hip/hip_runtime.h>

// MatchLSTM forward (Round 29): phase-A fusion.
//   R28 post-mortem: phase A 635us vs ~210 ideal. Losses: 17 dependent
//   small launches (tails), P fp32 roundtrip (50MB/half), mfma_nt at
//   1 block/CU = 2/4 SIMDs idle. R29:
//   (a) gather_fused: gather-GEMM computes ALL 3 GATES per block (mt=1,
//       acc[3][4]), adds biases, applies gate math, writes h directly as
//       RhB bf16 hi/lo frags -> P + enc_pack GONE. Grid (128,8), 8 wv/CU.
//   (b) fusedA<HYP>: nt + 3-gate GEMM in ONE launch (blockIdx.y<8 = nt,
//       >=8 = g3). Grid (32,32) = 4 blocks/CU uniform, 8 waves/CU.
//   Phase A: 17 -> 9 launches. Per-output MFMA sequence/k-order/gate math
//   unchanged -> BIT-IDENTICAL (absmax must stay 0.0009765625 exactly).
// phaseB (755us stable) + pack_wm: verbatim.

#define DEV static __device__ __forceinline__

DEV float fast_sigmoid(float x) { return 1.0f / (1.0f + __expf(-x)); }
DEV float fast_tanh(float x)    { return 1.0f - 2.0f / (__expf(2.0f * x) + 1.0f); }

DEV unsigned f2bf(float x) {
    unsigned v = __float_as_uint(x);
    return (v + 0x7FFFu + ((v >> 16) & 1u)) >> 16;
}
DEV float blo(unsigned u) { return __uint_as_float(u << 16); }

DEV float ntload(const float* p) { return __builtin_nontemporal_load(p); }

typedef __attribute__((ext_vector_type(8))) short bfrag;   // 8 bf16
typedef __attribute__((ext_vector_type(4))) float ffrag;   // 4 fp32 acc

// G3 block region (ushorts): 1536*64 data + 1024 pad = 99328 = 194KB
#define G3_BLK_S 99328

DEV void cvt_hilo(const float* v, bfrag& hi, bfrag& lo)
{
#pragma unroll
    for (int z = 0; z < 8; ++z) {
        unsigned h = f2bf(v[z]);
        hi[z] = (short)h;
        lo[z] = (short)f2bf(v[z] - __uint_as_float(h << 16));
    }
}

// ---------------------------------------------------------------------------
// gather_fused (R29): embed-gather 3-gate GEMM (K=300) + bias + LSTM gate
// math + RhB bf16 hi/lo A-frag pack, all in one kernel. Wave = 16 M-rows,
// all 3 gates; block = 2 waves = 32 rows. Grid (128, 8).
// ---------------------------------------------------------------------------
__global__ __launch_bounds__(128, 2) void gather_fused_kernel(
    const float* __restrict__ embed, const int* __restrict__ gidx,
    const float* __restrict__ Wih,          // 2048 x 300
    const float* __restrict__ bih, const float* __restrict__ bhh,
    unsigned short* __restrict__ RhB)
{
    const int wv   = threadIdx.x >> 6;
    const int lane = threadIdx.x & 63;
    const int row  = lane & 15;
    const int quad = lane >> 4;
    const int m0 = blockIdx.x * 32 + wv * 16;
    const int j0 = blockIdx.y * 64;

    const int arow = gidx[m0 + row];

    ffrag acc[3][4];                         // [gate][n]
#pragma unroll
    for (int g = 0; g < 3; ++g)
#pragma unroll
        for (int n = 0; n < 4; ++n)
#pragma unroll
            for (int r = 0; r < 4; ++r) acc[g][n][r] = 0.0f;

#pragma unroll 1
    for (int k0 = 0; k0 < 300; k0 += 32) {
        const bool tail = (k0 + 32 > 300);
        float av[8];
        if (!tail) {
            const float* ap = embed + (size_t)arow * 300 + k0 + quad * 8;
            float4 aA = *(const float4*)ap;
            float4 aB = *(const float4*)(ap + 4);
            av[0]=aA.x; av[1]=aA.y; av[2]=aA.z; av[3]=aA.w;
            av[4]=aB.x; av[5]=aB.y; av[6]=aB.z; av[7]=aB.w;
        } else {
#pragma unroll
            for (int z = 0; z < 8; ++z) {
                int kk = k0 + quad * 8 + z;
                av[z] = (kk < 300) ? embed[(size_t)arow * 300 + kk] : 0.0f;
            }
        }
        bfrag ahi, alo;
        cvt_hilo(av, ahi, alo);
#pragma unroll
        for (int g = 0; g < 3; ++g) {
            const int gbase = (g == 0) ? 0 : (g == 1 ? 1024 : 1536);
#pragma unroll
            for (int n = 0; n < 4; ++n) {
                const int wrow = gbase + j0 + n * 16 + row;
                float wvv[8];
                if (!tail) {
                    const float* wp = Wih + (size_t)wrow * 300 + k0 + quad * 8;
                    float4 wA = *(const float4*)wp;
                    float4 wB = *(const float4*)(wp + 4);
                    wvv[0]=wA.x; wvv[1]=wA.y; wvv[2]=wA.z; wvv[3]=wA.w;
                    wvv[4]=wB.x; wvv[5]=wB.y; wvv[6]=wB.z; wvv[7]=wB.w;
                } else {
#pragma unroll
                    for (int z = 0; z < 8; ++z) {
                        int kk = k0 + quad * 8 + z;
                        wvv[z] = (kk < 300) ? Wih[(size_t)wrow * 300 + kk] : 0.0f;
                    }
                }
                bfrag whi, wlo;
                cvt_hilo(wvv, whi, wlo);
                acc[g][n] = __builtin_amdgcn_mfma_f32_16x16x32_bf16(ahi, whi, acc[g][n], 0, 0, 0);
                acc[g][n] = __builtin_amdgcn_mfma_f32_16x16x32_bf16(alo, whi, acc[g][n], 0, 0, 0);
                acc[g][n] = __builtin_amdgcn_mfma_f32_16x16x32_bf16(ahi, wlo, acc[g][n], 0, 0, 0);
            }
        }
    }

    // Epilogue: bias + gate math + RhB fragment pack (validated layout).
#pragma unroll
    for (int n = 0; n < 4; ++n) {
        const int j = j0 + n * 16 + row;
        const float b0 = bih[j]        + bhh[j];
        const float b1 = bih[1024 + j] + bhh[1024 + j];
        const float b2 = bih[1536 + j] + bhh[1536 + j];
        const int kc     = j >> 5;
        const int lane_g = ((j >> 3) & 3) * 16;        // + (m&15)
        const int z      = j & 7;
#pragma unroll
        for (int r = 0; r < 4; ++r) {
            const int m = m0 + quad * 4 + r;
            float gi = acc[0][n][r] + b0;
            float gg = acc[1][n][r] + b1;
            float go = acc[2][n][r] + b2;
            float cc = fast_sigmoid(gi) * fast_tanh(gg);
            float hv = fast_sigmoid(go) * fast_tanh(cc);
            size_t idx = ((size_t)(kc * 256 + (m >> 4)) * 64
                          + lane_g + (m & 15)) * 16 + z;
            unsigned hb = f2bf(hv);
            RhB[idx]     = (unsigned short)hb;
            RhB[idx + 8] = (unsigned short)f2bf(hv - blo(hb));
        }
    }
}

// ---------------------------------------------------------------------------
// fusedA<HYP> (R29): one launch = nt GEMM (y<8) + 3-gate GEMM (y>=8).
//   nt: C[m][512] = A.Wnt^T -> outNT (fp32).
//   g3: HYP=0 -> G3s bf16 t-major (no bias); HYP=1 -> outMH fp32 + bias.
// A from RhB packed frags; 4 M-tiles/wave; block = 2 waves; grid (32,32).
// ---------------------------------------------------------------------------
template<int HYP>
__global__ __launch_bounds__(128, 2) void fusedA_kernel(
    const uint4* __restrict__ AB,
    const float* __restrict__ Wnt,          // Ws or Wt (512x512)
    const float* __restrict__ Wg3,          // Wih_m (+512 if HYP), ldw 1024
    const float* __restrict__ bias1, const float* __restrict__ bias2,
    float* __restrict__ outNT,              // pre_s/pre_t half
    unsigned short* __restrict__ G3s, int mbase,
    float* __restrict__ outMH)              // pre_m_h half (HYP)
{
    const int wv   = threadIdx.x >> 6;
    const int lane = threadIdx.x & 63;
    const int row  = lane & 15;
    const int quad = lane >> 4;
    const int m0   = blockIdx.x * 128 + wv * 64;
    const int mt0  = m0 >> 4;
    const int yy   = blockIdx.y;
    const bool isNT = (yy < 8);

    int gate = 0, j0 = 0, gbase = 0, wbase, ldw;
    const float* W;
    if (isNT) {
        W = Wnt; ldw = 512; wbase = yy * 64;
    } else {
        gate = (yy - 8) >> 3;
        j0   = ((yy - 8) & 7) * 64;
        gbase = (gate == 0) ? 0 : (gate == 1 ? 1024 : 1536);
        W = Wg3; ldw = 1024; wbase = gbase + j0;
    }

    ffrag acc[4][4];
#pragma unroll
    for (int mt = 0; mt < 4; ++mt)
#pragma unroll
        for (int n = 0; n < 4; ++n)
#pragma unroll
            for (int r = 0; r < 4; ++r) acc[mt][n][r] = 0.0f;

#pragma unroll 1
    for (int k0 = 0; k0 < 512; k0 += 32) {
        const int kc = k0 >> 5;
        bfrag ahi[4], alo[4];
#pragma unroll
        for (int mt = 0; mt < 4; ++mt) {
            const uint4* ap = AB + ((size_t)(kc * 256 + mt0 + mt) * 64 + lane) * 2;
            ahi[mt] = *(const bfrag*)(ap);
            alo[mt] = *(const bfrag*)(ap + 1);
        }
#pragma unroll
        for (int n = 0; n < 4; ++n) {
            const int wrow = wbase + n * 16 + row;
            const float* wp = W + (size_t)wrow * ldw + k0 + quad * 8;
            float4 wA = *(const float4*)wp;
            float4 wB = *(const float4*)(wp + 4);
            float wvv[8] = {wA.x, wA.y, wA.z, wA.w, wB.x, wB.y, wB.z, wB.w};
            bfrag whi, wlo;
            cvt_hilo(wvv, whi, wlo);
#pragma unroll
            for (int mt = 0; mt < 4; ++mt) {
                acc[mt][n] = __builtin_amdgcn_mfma_f32_16x16x32_bf16(ahi[mt], whi, acc[mt][n], 0, 0, 0);
                acc[mt][n] = __builtin_amdgcn_mfma_f32_16x16x32_bf16(alo[mt], whi, acc[mt][n], 0, 0, 0);
                acc[mt][n] = __builtin_amdgcn_mfma_f32_16x16x32_bf16(ahi[mt], wlo, acc[mt][n], 0, 0, 0);
            }
        }
    }

    if (isNT) {
#pragma unroll
        for (int mt = 0; mt < 4; ++mt)
#pragma unroll
            for (int n = 0; n < 4; ++n)
#pragma unroll
                for (int r = 0; r < 4; ++r)
                    outNT[(size_t)(m0 + mt * 16 + quad * 4 + r) * 512
                          + wbase + n * 16 + row] = acc[mt][n][r];
    } else if (!HYP) {
#pragma unroll
        for (int n = 0; n < 4; ++n) {
            const int j = j0 + n * 16 + row;
#pragma unroll
            for (int mt = 0; mt < 4; ++mt)
#pragma unroll
                for (int r = 0; r < 4; ++r) {
                    const int mg = mbase + m0 + mt * 16 + quad * 4 + r;
                    const int t = mg >> 7, b = mg & 127;
                    size_t idx = (size_t)b * G3_BLK_S
                               + ((size_t)(gate * 512 + j)) * 64 + t;
                    G3s[idx] = (unsigned short)f2bf(acc[mt][n][r]);
                }
        }
    } else {
#pragma unroll
        for (int n = 0; n < 4; ++n) {
            const int j = j0 + n * 16 + row;
            const float bb = bias1[gbase + j] + bias2[gbase + j];
#pragma unroll
            for (int mt = 0; mt < 4; ++mt)
#pragma unroll
                for (int r = 0; r < 4; ++r) {
                    const int m = m0 + mt * 16 + quad * 4 + r;
                    outMH[((size_t)m * 3 + gate) * 512 + j] = acc[mt][n][r] + bb;
                }
        }
    }
}

// ---------------------------------------------------------------------------
// Wm pack (validated R19): [kc][nt][lane] tile-interleaved.
// ---------------------------------------------------------------------------
__global__ __launch_bounds__(256) void pack_wm_kernel(
    const float* __restrict__ Wm, unsigned* __restrict__ WmB)
{
    int i = blockIdx.x * 256 + threadIdx.x;           // 0 .. 131071
    int u = i & 3, lane = (i >> 2) & 63;
    int nt = (i >> 8) & 31, kc = i >> 13;
    int row = nt * 16 + (lane & 15);
    int k = kc * 32 + ((lane >> 4) << 3) + u * 2;
    unsigned lo = f2bf(Wm[(size_t)row * 512 + k]);
    unsigned hi = f2bf(Wm[(size_t)row * 512 + k + 1]);
    WmB[i] = lo | (hi << 16);
}

// ---------------------------------------------------------------------------
// Phase B (R25 verbatim): GEMV1 K-split + MFMA G3-sum (t-major).
// ---------------------------------------------------------------------------
__global__ __launch_bounds__(1024) void phaseB_kernel(
    const float* __restrict__ pre_s, const float* __restrict__ pre_t,
    const float* __restrict__ pre_m_h,
    const unsigned* __restrict__ WmB, const unsigned short* __restrict__ G3s,
    const float* __restrict__ w_e,
    const float* __restrict__ fc_w,  const float* __restrict__ fc_b,
    float* __restrict__ out)
{
    extern __shared__ __align__(16) float psL[];      // 64*512 fp32 = 128KB
    __shared__ __align__(16) float hm[512];
    __shared__ __align__(16) float base[512];
    __shared__ __align__(16) float wesh[512];
    __shared__ __align__(16) float sc[64];
    __shared__ __align__(16) float red[2 * 512];
    __shared__ __align__(16) float gates3[1536];
    __shared__ __align__(16) unsigned short hmh[512];
    __shared__ __align__(16) unsigned short hml[512];
    __shared__ __align__(16) unsigned short sch[64];
    __shared__ __align__(16) unsigned short scl[64];

    const int b    = blockIdx.x;
    const int tid  = threadIdx.x;
    const int wv   = tid >> 6;
    const int lane = tid & 63;
    const int col  = lane & 15;
    const int quad = lane >> 4;

    if (tid < 512) {
        wesh[tid] = w_e[tid];
        hm[tid] = 0.0f; hmh[tid] = 0; hml[tid] = 0;
    }
    for (int i = tid; i < 32768; i += 1024) {
        int t = i >> 9, h = i & 511;
        psL[i] = ntload(&pre_s[((size_t)t * 128 + b) * 512 + h]);
    }
    __syncthreads();

    for (int k = 0; k < 64; ++k) {
        // ---- GEMV1 (K-split): partials for base = Wm . hm
        {
            const int kh2 = wv >> 3;
            const int tp  = (wv & 7) * 4;
            ffrag a0 = {0.0f,0.0f,0.0f,0.0f}, a1 = {0.0f,0.0f,0.0f,0.0f};
            ffrag a2 = {0.0f,0.0f,0.0f,0.0f}, a3 = {0.0f,0.0f,0.0f,0.0f};
            const uint4* wp = (const uint4*)WmB
                            + ((size_t)(kh2 * 8) * 32 + tp) * 64 + lane;
            const unsigned short* ab = ((lane & 8) == 0) ? hmh : hml;
#pragma unroll 1
            for (int kc = 0; kc < 8; ++kc) {
                bfrag a  = *(const bfrag*)&ab[(kh2 * 8 + kc) * 32 + quad * 8];
                bfrag w0 = *(const bfrag*)(wp);
                bfrag w1 = *(const bfrag*)(wp + 64);
                bfrag w2 = *(const bfrag*)(wp + 128);
                bfrag w3 = *(const bfrag*)(wp + 192);
                a0 = __builtin_amdgcn_mfma_f32_16x16x32_bf16(a, w0, a0, 0, 0, 0);
                a1 = __builtin_amdgcn_mfma_f32_16x16x32_bf16(a, w1, a1, 0, 0, 0);
                a2 = __builtin_amdgcn_mfma_f32_16x16x32_bf16(a, w2, a2, 0, 0, 0);
                a3 = __builtin_amdgcn_mfma_f32_16x16x32_bf16(a, w3, a3, 0, 0, 0);
                wp += 2048;
            }
            float s0 = a0[0] + __shfl_xor(a0[0], 32);
            float s1 = a1[0] + __shfl_xor(a1[0], 32);
            float s2 = a2[0] + __shfl_xor(a2[0], 32);
            float s3 = a3[0] + __shfl_xor(a3[0], 32);
            if (lane < 16) {
                float* rr = &red[kh2 * 512];
                rr[(tp + 0) * 16 + lane] = s0;
                rr[(tp + 1) * 16 + lane] = s1;
                rr[(tp + 2) * 16 + lane] = s2;
                rr[(tp + 3) * 16 + lane] = s3;
            }
        }
        __syncthreads();
        if (tid < 512)
            base[tid] = red[tid] + red[512 + tid]
                      + ntload(&pre_t[((size_t)k * 128 + b) * 512 + tid]);
        __syncthreads();

        // ---- attention scores: e[t] = w_e . tanh(psL[t] + base)  (all LDS)
#pragma unroll
        for (int tt = 0; tt < 4; ++tt) {
            int t = wv * 4 + tt;
            const float* ps = &psL[t * 512];
            float p = 0.0f;
#pragma unroll
            for (int u = 0; u < 8; ++u) {
                int h = lane + 64 * u;
                p += wesh[h] * fast_tanh(ps[h] + base[h]);
            }
#pragma unroll
            for (int off = 32; off; off >>= 1) p += __shfl_xor(p, off);
            if (lane == 0) sc[t] = p;
        }
        __syncthreads();

        // ---- softmax (+ bf16 hi/lo pack of alpha)
        if (wv == 0) {
            float s = sc[lane], mx = s;
#pragma unroll
            for (int off = 32; off; off >>= 1) mx = fmaxf(mx, __shfl_xor(mx, off));
            float e = __expf(s - mx), sum = e;
#pragma unroll
            for (int off = 32; off; off >>= 1) sum += __shfl_xor(sum, off);
            float a = e / sum;
            unsigned hb = f2bf(a);
            sch[lane] = (unsigned short)hb;
            scl[lane] = (unsigned short)f2bf(a - blo(hb));
        }
        __syncthreads();

        // ---- gates = sum_t alpha_t * G3T[b][:,t]  via MFMA (K=64)
        {
            const unsigned short* ab = ((lane & 8) == 0) ? sch : scl;
            bfrag aA = *(const bfrag*)&ab[quad * 8];
            bfrag aB = *(const bfrag*)&ab[32 + quad * 8];
            const unsigned short* gp = G3s + (size_t)b * G3_BLK_S
                                     + ((size_t)(wv * 96) + col) * 64 + quad * 8;
            ffrag g[6];
#pragma unroll
            for (int t6 = 0; t6 < 6; ++t6) {
                g[t6][0] = 0.0f; g[t6][1] = 0.0f; g[t6][2] = 0.0f; g[t6][3] = 0.0f;
            }
#pragma unroll
            for (int t6 = 0; t6 < 6; ++t6) {
                bfrag w0 = *(const bfrag*)(gp + t6 * 1024);
                g[t6] = __builtin_amdgcn_mfma_f32_16x16x32_bf16(aA, w0, g[t6], 0, 0, 0);
            }
#pragma unroll
            for (int t6 = 0; t6 < 6; ++t6) {
                bfrag w1 = *(const bfrag*)(gp + t6 * 1024 + 32);
                g[t6] = __builtin_amdgcn_mfma_f32_16x16x32_bf16(aB, w1, g[t6], 0, 0, 0);
            }
#pragma unroll
            for (int t6 = 0; t6 < 6; ++t6) {
                float s = g[t6][0] + __shfl_xor(g[t6][0], 32);
                if (lane < 16) gates3[(wv * 6 + t6) * 16 + lane] = s;
            }
        }
        __syncthreads();

        // ---- gate math -> hm (+ hi/lo pack for next step's GEMV1)
        if (tid < 512) {
            const size_t m = (size_t)k * 128 + b;
            float gi = gates3[tid]        + ntload(&pre_m_h[(m * 3 + 0) * 512 + tid]);
            float gg = gates3[512 + tid]  + ntload(&pre_m_h[(m * 3 + 1) * 512 + tid]);
            float go = gates3[1024 + tid] + ntload(&pre_m_h[(m * 3 + 2) * 512 + tid]);
            float cc = fast_sigmoid(gi) * fast_tanh(gg);
            float hv = fast_sigmoid(go) * fast_tanh(cc);
            hm[tid] = hv;
            unsigned hb = f2bf(hv);
            hmh[tid] = (unsigned short)hb;
            hml[tid] = (unsigned short)f2bf(hv - blo(hb));
        }
        __syncthreads();
    }

    if (wv < 3) {
        float p = 0.0f;
#pragma unroll
        for (int u = 0; u < 8; ++u) {
            int h = lane + 64 * u;
            p += hm[h] * fc_w[wv * 512 + h];
        }
#pragma unroll
        for (int off = 32; off; off >>= 1) p += __shfl_xor(p, off);
        if (lane == 0) out[b * 3 + wv] = p + fc_b[wv];
    }
}

extern "C" void kernel_launch(void* const* d_in, const int* in_sizes, int n_in,
                              void* d_out, int out_size, void* d_ws, size_t ws_size,
                              hipStream_t stream)
{
    (void)in_sizes; (void)n_in; (void)out_size;
    const int*   premise    = (const int*)d_in[0];
    const int*   hypothesis = (const int*)d_in[2];
    const float* embed  = (const float*)d_in[4];
    const float* w_e    = (const float*)d_in[5];
    const float* Ws     = (const float*)d_in[6];
    const float* Wt     = (const float*)d_in[7];
    const float* Wm     = (const float*)d_in[8];
    const float* Wih_p  = (const float*)d_in[9];
    const float* bih_p  = (const float*)d_in[10];
    const float* bhh_p  = (const float*)d_in[11];
    const float* Wih_h  = (const float*)d_in[12];
    const float* bih_h  = (const float*)d_in[13];
    const float* bhh_h  = (const float*)d_in[14];
    const float* Wih_m  = (const float*)d_in[15];
    const float* bih_m  = (const float*)d_in[16];
    const float* bhh_m  = (const float*)d_in[17];
    const float* fc_w   = (const float*)d_in[18];
    const float* fc_b   = (const float*)d_in[19];

    // Workspace layout (floats), total 29,425,664 <= guard 29,556,736:
    //   RhB     @ 0         : 2,097,152  (bf16 hi/lo A-frags; WmB aliases)
    //   pre_s   @ 2,097,152 : 4,194,304
    //   pre_t   @ 6,291,456 : 4,194,304
    //   pre_m_h @10,485,760 :12,582,912
    //   G3      @23,068,672 : 6,356,992  (bf16 t-major, 194KB/block padded)
    float* ws      = (float*)d_ws;
    unsigned short* RhB = (unsigned short*)ws;
    const uint4* RhB4   = (const uint4*)ws;
    float* pre_s   = ws + 2097152;
    float* pre_t   = ws + 6291456;
    float* pre_m_h = ws + 10485760;
    unsigned short* G3s = (unsigned short*)(ws + 23068672);
    unsigned* WmB  = (unsigned*)ws;           // aliases RhB after last reader
    float* outp    = (float*)d_out;
    if (ws_size < (size_t)29556736 * 4) return;

    dim3 blk2(128);
    dim3 blk(256);

    // ---- Phase A: premise halves -> RhB(half) -> {pre_s(half), G3(half)}
    for (int h = 0; h < 2; ++h) {
        gather_fused_kernel<<<dim3(128, 8), blk2, 0, stream>>>(
            embed, premise + h * 4096, Wih_p, bih_p, bhh_p, RhB);
        fusedA_kernel<0><<<dim3(32, 32), blk2, 0, stream>>>(
            RhB4, Ws, Wih_m, nullptr, nullptr,
            pre_s + (size_t)h * 2097152, G3s, h * 4096, nullptr);
    }
    // ---- Phase A: hypothesis halves -> RhB(half) -> {pre_t(half), pre_m_h(half)}
    for (int h = 0; h < 2; ++h) {
        gather_fused_kernel<<<dim3(128, 8), blk2, 0, stream>>>(
            embed, hypothesis + h * 4096, Wih_h, bih_h, bhh_h, RhB);
        fusedA_kernel<1><<<dim3(32, 32), blk2, 0, stream>>>(
            RhB4, Wt, Wih_m + 512, bih_m, bhh_m,
            pre_t + (size_t)h * 2097152, nullptr, 0,
            pre_m_h + (size_t)h * 6291456);
    }

    // ---- Wm pack (after RhB's last reader; output aliases RhB)
    pack_wm_kernel<<<512, blk, 0, stream>>>(Wm, WmB);

    // ---- Phase B (128KB dynamic LDS for pre_s cache)
    static int attr_done = 0;
    if (!attr_done) {
        hipFuncSetAttribute((const void*)phaseB_kernel,
                            hipFuncAttributeMaxDynamicSharedMemorySize, 131072);
        attr_done = 1;
    }
    phaseB_kernel<<<dim3(128), dim3(1024), 131072, stream>>>(
        pre_s, pre_t, pre_m_h, WmB, G3s, w_e, fc_w, fc_b, outp);
}